// Round 1
// baseline (637.863 us; speedup 1.0000x reference)
//
#include <hip/hip_runtime.h>
#include <hip/hip_bf16.h>
#include <math.h>

// ---------------------------------------------------------------------------
// GraphSAGE (gcn aggregator) x3 layers, fp32.
//   h = (segment_sum(x[src], dst) + x) / (deg+1);  out = act(h @ W.T + b)
// Strategy: build CSR (by dst) in workspace each call, node-parallel gather
// aggregation (1 wave = 1 node, no float atomics), LDS-tiled fp32 GEMM with
// fused bias+activation.
// ---------------------------------------------------------------------------

#define NFEAT 128  // input/hidden feature dim (fixed by problem)

// ---- CSR build ------------------------------------------------------------

__global__ void count_kernel(const int* __restrict__ dst, int* __restrict__ cnt, int E) {
    int e = blockIdx.x * blockDim.x + threadIdx.x;
    if (e < E) atomicAdd(&cnt[dst[e]], 1);
}

// single block, 1024 threads: exclusive scan of cnt -> row_ptr, cursor, deg_inv
__global__ __launch_bounds__(1024) void scan_kernel(const int* __restrict__ cnt,
                                                    int* __restrict__ row_ptr,
                                                    int* __restrict__ cursor,
                                                    float* __restrict__ deg_inv,
                                                    int N) {
    __shared__ int part[1024];
    const int t = threadIdx.x;
    const int CH = (N + 1023) / 1024;  // chunk per thread
    int lo = t * CH;
    int hi = lo + CH; if (hi > N) hi = N;
    int s = 0;
    for (int i = lo; i < hi && i >= 0; ++i) s += cnt[i];
    part[t] = s;
    __syncthreads();
    // inclusive Hillis-Steele scan over 1024 partials
    for (int off = 1; off < 1024; off <<= 1) {
        int val = (t >= off) ? part[t - off] : 0;
        __syncthreads();
        part[t] += val;
        __syncthreads();
    }
    int run = (t == 0) ? 0 : part[t - 1];
    for (int i = lo; i < hi; ++i) {
        int c = cnt[i];
        row_ptr[i] = run;
        cursor[i]  = run;
        deg_inv[i] = 1.0f / (float)(c + 1);
        run += c;
    }
    if (t == 1023) row_ptr[N] = part[1023];
}

__global__ void fill_kernel(const int* __restrict__ src, const int* __restrict__ dst,
                            int* __restrict__ cursor, int* __restrict__ col_idx, int E) {
    int e = blockIdx.x * blockDim.x + threadIdx.x;
    if (e < E) {
        int p = atomicAdd(&cursor[dst[e]], 1);
        col_idx[p] = src[e];
    }
}

// ---- Aggregation: one wave per node, 64 lanes x float2 = 128 feats --------

__global__ __launch_bounds__(256) void aggregate_kernel(const float* __restrict__ X,
                                                        const int* __restrict__ row_ptr,
                                                        const int* __restrict__ col_idx,
                                                        const float* __restrict__ deg_inv,
                                                        float* __restrict__ H, int N) {
    const int wave = blockIdx.x * (blockDim.x >> 6) + (threadIdx.x >> 6);
    const int lane = threadIdx.x & 63;
    if (wave >= N) return;
    const int v   = wave;
    const int beg = row_ptr[v];
    const int end = row_ptr[v + 1];

    float2 acc0 = make_float2(0.f, 0.f);
    float2 acc1 = make_float2(0.f, 0.f);
    int e = beg;
    for (; e + 1 < end; e += 2) {
        int s0 = col_idx[e];
        int s1 = col_idx[e + 1];
        float2 t0 = *(const float2*)(X + (size_t)s0 * NFEAT + lane * 2);
        float2 t1 = *(const float2*)(X + (size_t)s1 * NFEAT + lane * 2);
        acc0.x += t0.x; acc0.y += t0.y;
        acc1.x += t1.x; acc1.y += t1.y;
    }
    if (e < end) {
        int s0 = col_idx[e];
        float2 t0 = *(const float2*)(X + (size_t)s0 * NFEAT + lane * 2);
        acc0.x += t0.x; acc0.y += t0.y;
    }
    float2 xs = *(const float2*)(X + (size_t)v * NFEAT + lane * 2);
    float inv = deg_inv[v];
    float2 r;
    r.x = (acc0.x + acc1.x + xs.x) * inv;
    r.y = (acc0.y + acc1.y + xs.y) * inv;
    *(float2*)(H + (size_t)v * NFEAT + lane * 2) = r;
}

// ---- GEMM: out[N,OUT] = act(H[N,128] @ W[OUT,128]^T + b) ------------------
// 64x64 tile per block (256 thr), 4x4 microtile, k-tiled by 16 through LDS.
// act: 0 = relu, 1 = sigmoid

__global__ __launch_bounds__(256) void gemm_act_kernel(const float* __restrict__ H,
                                                       const float* __restrict__ W,
                                                       const float* __restrict__ bias,
                                                       float* __restrict__ out,
                                                       int N, int OUT, int act) {
    __shared__ float Hs[16][65];  // [kk][row], pad 65 to spread banks
    __shared__ float Ws[16][65];  // [kk][col]
    const int t    = threadIdx.x;
    const int row0 = blockIdx.x * 64;
    const int col0 = blockIdx.y * 64;
    const int tx   = t & 15;   // col group
    const int ty   = t >> 4;   // row group
    const int lr   = t >> 2;         // staging row/col 0..63
    const int kq   = (t & 3) * 4;    // staging k offset

    float acc[4][4] = {};

    for (int k0 = 0; k0 < NFEAT; k0 += 16) {
        float4 hv = make_float4(0.f, 0.f, 0.f, 0.f);
        const int gr = row0 + lr;
        if (gr < N) hv = *(const float4*)(H + (size_t)gr * NFEAT + k0 + kq);
        float4 wv = *(const float4*)(W + (size_t)(col0 + lr) * NFEAT + k0 + kq);
        __syncthreads();  // protect previous iteration's reads
        Hs[kq + 0][lr] = hv.x; Hs[kq + 1][lr] = hv.y; Hs[kq + 2][lr] = hv.z; Hs[kq + 3][lr] = hv.w;
        Ws[kq + 0][lr] = wv.x; Ws[kq + 1][lr] = wv.y; Ws[kq + 2][lr] = wv.z; Ws[kq + 3][lr] = wv.w;
        __syncthreads();
#pragma unroll
        for (int kk = 0; kk < 16; ++kk) {
            float4 a = *(const float4*)&Hs[kk][ty * 4];
            float4 b = *(const float4*)&Ws[kk][tx * 4];
            float av[4] = {a.x, a.y, a.z, a.w};
            float bv[4] = {b.x, b.y, b.z, b.w};
#pragma unroll
            for (int i = 0; i < 4; ++i)
#pragma unroll
                for (int j = 0; j < 4; ++j) acc[i][j] += av[i] * bv[j];
        }
    }

#pragma unroll
    for (int i = 0; i < 4; ++i) {
        int r = row0 + ty * 4 + i;
        if (r >= N) break;
#pragma unroll
        for (int j = 0; j < 4; ++j) {
            int c = col0 + tx * 4 + j;
            float v = acc[i][j] + bias[c];
            if (act == 0) {
                v = v > 0.f ? v : 0.f;
            } else {
                v = 1.0f / (1.0f + __expf(-v));
            }
            out[(size_t)r * OUT + c] = v;
        }
    }
}

// ---------------------------------------------------------------------------

static inline size_t align256(size_t x) { return (x + 255) & ~(size_t)255; }

extern "C" void kernel_launch(void* const* d_in, const int* in_sizes, int n_in,
                              void* d_out, int out_size, void* d_ws, size_t ws_size,
                              hipStream_t stream) {
    const float* x   = (const float*)d_in[0];
    const int*   src = (const int*)d_in[1];
    const int*   dst = (const int*)d_in[2];
    const float* W1  = (const float*)d_in[3];
    const float* b1  = (const float*)d_in[4];
    const float* W2  = (const float*)d_in[5];
    const float* b2  = (const float*)d_in[6];
    const float* W3  = (const float*)d_in[7];
    const float* b3  = (const float*)d_in[8];
    float*       out = (float*)d_out;

    const int N = in_sizes[0] / NFEAT;     // 50000
    const int E = in_sizes[1];             // 800000
    const int D_OUT = in_sizes[7] / NFEAT; // 64

    // workspace carve
    char* ws = (char*)d_ws;
    int* cnt      = (int*)ws;                 ws += align256((size_t)N * 4);
    int* row_ptr  = (int*)ws;                 ws += align256((size_t)(N + 1) * 4);
    int* cursor   = (int*)ws;                 ws += align256((size_t)N * 4);
    int* col_idx  = (int*)ws;                 ws += align256((size_t)E * 4);
    float* deg_inv = (float*)ws;              ws += align256((size_t)N * 4);
    float* hA     = (float*)ws;               ws += align256((size_t)N * NFEAT * 4);
    float* hB     = (float*)ws;               ws += align256((size_t)N * NFEAT * 4);

    // ---- CSR build (ws is re-poisoned every call, so rebuild every call) ----
    hipMemsetAsync(cnt, 0, (size_t)N * 4, stream);
    {
        int blocks = (E + 255) / 256;
        count_kernel<<<blocks, 256, 0, stream>>>(dst, cnt, E);
        scan_kernel<<<1, 1024, 0, stream>>>(cnt, row_ptr, cursor, deg_inv, N);
        fill_kernel<<<blocks, 256, 0, stream>>>(src, dst, cursor, col_idx, E);
    }

    const int aggBlocks = (N + 3) / 4;  // 4 waves/block, 1 wave/node
    dim3 gemmGrid128((N + 63) / 64, NFEAT / 64);
    dim3 gemmGridOut((N + 63) / 64, D_OUT / 64);

    // layer 1: x -> hA -> hB (relu)
    aggregate_kernel<<<aggBlocks, 256, 0, stream>>>(x, row_ptr, col_idx, deg_inv, hA, N);
    gemm_act_kernel<<<gemmGrid128, 256, 0, stream>>>(hA, W1, b1, hB, N, NFEAT, 0);

    // layer 2: hB -> hA -> hB' (relu)  (reuse hA as agg buffer, write gemm to hA? no: ping-pong)
    aggregate_kernel<<<aggBlocks, 256, 0, stream>>>(hB, row_ptr, col_idx, deg_inv, hA, N);
    gemm_act_kernel<<<gemmGrid128, 256, 0, stream>>>(hA, W2, b2, hB, N, NFEAT, 0);

    // layer 3: hB -> hA -> out (sigmoid, 64 cols)
    aggregate_kernel<<<aggBlocks, 256, 0, stream>>>(hB, row_ptr, col_idx, deg_inv, hA, N);
    gemm_act_kernel<<<gemmGridOut, 256, 0, stream>>>(hA, W3, b3, out, N, D_OUT, 1);
}

// Round 2
// 506.334 us; speedup vs baseline: 1.2598x; 1.2598x over previous
//
#include <hip/hip_runtime.h>
#include <hip/hip_bf16.h>
#include <math.h>

// ---------------------------------------------------------------------------
// GraphSAGE (gcn aggregator) x3 layers, fp32.
//   h = (segment_sum(x[src], dst) + x) / (deg+1);  out = act(h @ W.T + b)
// R2: replaced single-block scan (135 us, 1 CU) with 3-phase parallel scan.
// ---------------------------------------------------------------------------

#define NFEAT 128
#define SCAN_CHUNK 1024  // elements per block in the scan (256 thr x int4)

// ---- CSR build ------------------------------------------------------------

__global__ void count_kernel(const int* __restrict__ dst, int* __restrict__ cnt, int E) {
    int e = blockIdx.x * blockDim.x + threadIdx.x;
    if (e < E) atomicAdd(&cnt[dst[e]], 1);
}

// Phase A: per-block sums of 1024-element chunks.
__global__ __launch_bounds__(256) void scan_partial_kernel(const int* __restrict__ cnt,
                                                           int* __restrict__ blockSums, int N) {
    __shared__ int red[256];
    const int t = threadIdx.x;
    const int idx = blockIdx.x * SCAN_CHUNK + t * 4;
    int s = 0;
#pragma unroll
    for (int j = 0; j < 4; ++j)
        if (idx + j < N) s += cnt[idx + j];
    red[t] = s;
    __syncthreads();
    for (int off = 128; off > 0; off >>= 1) {
        if (t < off) red[t] += red[t + off];
        __syncthreads();
    }
    if (t == 0) blockSums[blockIdx.x] = red[0];
}

// Phase B: single small block scans the (<=256) block sums -> exclusive offsets.
__global__ __launch_bounds__(256) void scan_offsets_kernel(const int* __restrict__ blockSums,
                                                           int* __restrict__ blockOffs,
                                                           int nb, int* __restrict__ row_ptr, int N) {
    __shared__ int red[256];
    const int t = threadIdx.x;
    int v = (t < nb) ? blockSums[t] : 0;
    red[t] = v;
    __syncthreads();
    for (int off = 1; off < 256; off <<= 1) {
        int w = (t >= off) ? red[t - off] : 0;
        __syncthreads();
        red[t] += w;
        __syncthreads();
    }
    if (t < nb) blockOffs[t] = (t == 0) ? 0 : red[t - 1];
    if (t == 255) row_ptr[N] = red[255];  // total edge count
}

// Phase C: local exclusive scan per chunk + fill row_ptr/cursor/deg_inv.
__global__ __launch_bounds__(256) void scan_fill_kernel(const int* __restrict__ cnt,
                                                        const int* __restrict__ blockOffs,
                                                        int* __restrict__ row_ptr,
                                                        int* __restrict__ cursor,
                                                        float* __restrict__ deg_inv, int N) {
    __shared__ int red[256];
    const int t = threadIdx.x;
    const int idx = blockIdx.x * SCAN_CHUNK + t * 4;
    int c[4];
    int s = 0;
#pragma unroll
    for (int j = 0; j < 4; ++j) {
        c[j] = (idx + j < N) ? cnt[idx + j] : 0;
        s += c[j];
    }
    red[t] = s;
    __syncthreads();
    for (int off = 1; off < 256; off <<= 1) {
        int w = (t >= off) ? red[t - off] : 0;
        __syncthreads();
        red[t] += w;
        __syncthreads();
    }
    int run = ((t == 0) ? 0 : red[t - 1]) + blockOffs[blockIdx.x];
#pragma unroll
    for (int j = 0; j < 4; ++j) {
        if (idx + j < N) {
            row_ptr[idx + j] = run;
            cursor[idx + j]  = run;
            deg_inv[idx + j] = 1.0f / (float)(c[j] + 1);
            run += c[j];
        }
    }
}

__global__ void fill_kernel(const int* __restrict__ src, const int* __restrict__ dst,
                            int* __restrict__ cursor, int* __restrict__ col_idx, int E) {
    int e = blockIdx.x * blockDim.x + threadIdx.x;
    if (e < E) {
        int p = atomicAdd(&cursor[dst[e]], 1);
        col_idx[p] = src[e];
    }
}

// ---- Aggregation: one wave per node, 64 lanes x float2 = 128 feats --------

__global__ __launch_bounds__(256) void aggregate_kernel(const float* __restrict__ X,
                                                        const int* __restrict__ row_ptr,
                                                        const int* __restrict__ col_idx,
                                                        const float* __restrict__ deg_inv,
                                                        float* __restrict__ H, int N) {
    const int wave = blockIdx.x * (blockDim.x >> 6) + (threadIdx.x >> 6);
    const int lane = threadIdx.x & 63;
    if (wave >= N) return;
    const int v   = wave;
    const int beg = row_ptr[v];
    const int end = row_ptr[v + 1];

    float2 acc0 = make_float2(0.f, 0.f);
    float2 acc1 = make_float2(0.f, 0.f);
    int e = beg;
    for (; e + 1 < end; e += 2) {
        int s0 = col_idx[e];
        int s1 = col_idx[e + 1];
        float2 t0 = *(const float2*)(X + (size_t)s0 * NFEAT + lane * 2);
        float2 t1 = *(const float2*)(X + (size_t)s1 * NFEAT + lane * 2);
        acc0.x += t0.x; acc0.y += t0.y;
        acc1.x += t1.x; acc1.y += t1.y;
    }
    if (e < end) {
        int s0 = col_idx[e];
        float2 t0 = *(const float2*)(X + (size_t)s0 * NFEAT + lane * 2);
        acc0.x += t0.x; acc0.y += t0.y;
    }
    float2 xs = *(const float2*)(X + (size_t)v * NFEAT + lane * 2);
    float inv = deg_inv[v];
    float2 r;
    r.x = (acc0.x + acc1.x + xs.x) * inv;
    r.y = (acc0.y + acc1.y + xs.y) * inv;
    *(float2*)(H + (size_t)v * NFEAT + lane * 2) = r;
}

// ---- GEMM: out[N,OUT] = act(H[N,128] @ W[OUT,128]^T + b) ------------------

__global__ __launch_bounds__(256) void gemm_act_kernel(const float* __restrict__ H,
                                                       const float* __restrict__ W,
                                                       const float* __restrict__ bias,
                                                       float* __restrict__ out,
                                                       int N, int OUT, int act) {
    __shared__ float Hs[16][65];
    __shared__ float Ws[16][65];
    const int t    = threadIdx.x;
    const int row0 = blockIdx.x * 64;
    const int col0 = blockIdx.y * 64;
    const int tx   = t & 15;
    const int ty   = t >> 4;
    const int lr   = t >> 2;
    const int kq   = (t & 3) * 4;

    float acc[4][4] = {};

    for (int k0 = 0; k0 < NFEAT; k0 += 16) {
        float4 hv = make_float4(0.f, 0.f, 0.f, 0.f);
        const int gr = row0 + lr;
        if (gr < N) hv = *(const float4*)(H + (size_t)gr * NFEAT + k0 + kq);
        float4 wv = *(const float4*)(W + (size_t)(col0 + lr) * NFEAT + k0 + kq);
        __syncthreads();
        Hs[kq + 0][lr] = hv.x; Hs[kq + 1][lr] = hv.y; Hs[kq + 2][lr] = hv.z; Hs[kq + 3][lr] = hv.w;
        Ws[kq + 0][lr] = wv.x; Ws[kq + 1][lr] = wv.y; Ws[kq + 2][lr] = wv.z; Ws[kq + 3][lr] = wv.w;
        __syncthreads();
#pragma unroll
        for (int kk = 0; kk < 16; ++kk) {
            float4 a = *(const float4*)&Hs[kk][ty * 4];
            float4 b = *(const float4*)&Ws[kk][tx * 4];
            float av[4] = {a.x, a.y, a.z, a.w};
            float bv[4] = {b.x, b.y, b.z, b.w};
#pragma unroll
            for (int i = 0; i < 4; ++i)
#pragma unroll
                for (int j = 0; j < 4; ++j) acc[i][j] += av[i] * bv[j];
        }
    }

#pragma unroll
    for (int i = 0; i < 4; ++i) {
        int r = row0 + ty * 4 + i;
        if (r >= N) break;
#pragma unroll
        for (int j = 0; j < 4; ++j) {
            int c = col0 + tx * 4 + j;
            float v = acc[i][j] + bias[c];
            if (act == 0) {
                v = v > 0.f ? v : 0.f;
            } else {
                v = 1.0f / (1.0f + __expf(-v));
            }
            out[(size_t)r * OUT + c] = v;
        }
    }
}

// ---------------------------------------------------------------------------

static inline size_t align256(size_t x) { return (x + 255) & ~(size_t)255; }

extern "C" void kernel_launch(void* const* d_in, const int* in_sizes, int n_in,
                              void* d_out, int out_size, void* d_ws, size_t ws_size,
                              hipStream_t stream) {
    const float* x   = (const float*)d_in[0];
    const int*   src = (const int*)d_in[1];
    const int*   dst = (const int*)d_in[2];
    const float* W1  = (const float*)d_in[3];
    const float* b1  = (const float*)d_in[4];
    const float* W2  = (const float*)d_in[5];
    const float* b2  = (const float*)d_in[6];
    const float* W3  = (const float*)d_in[7];
    const float* b3  = (const float*)d_in[8];
    float*       out = (float*)d_out;

    const int N = in_sizes[0] / NFEAT;     // 50000
    const int E = in_sizes[1];             // 800000
    const int D_OUT = in_sizes[7] / NFEAT; // 64
    const int NB = (N + SCAN_CHUNK - 1) / SCAN_CHUNK;  // 49 scan blocks

    // workspace carve
    char* ws = (char*)d_ws;
    int* cnt       = (int*)ws;  ws += align256((size_t)N * 4);
    int* row_ptr   = (int*)ws;  ws += align256((size_t)(N + 1) * 4);
    int* cursor    = (int*)ws;  ws += align256((size_t)N * 4);
    int* col_idx   = (int*)ws;  ws += align256((size_t)E * 4);
    float* deg_inv = (float*)ws; ws += align256((size_t)N * 4);
    int* blockSums = (int*)ws;  ws += align256((size_t)NB * 4);
    int* blockOffs = (int*)ws;  ws += align256((size_t)NB * 4);
    float* hA      = (float*)ws; ws += align256((size_t)N * NFEAT * 4);
    float* hB      = (float*)ws; ws += align256((size_t)N * NFEAT * 4);

    // ---- CSR build ----
    hipMemsetAsync(cnt, 0, (size_t)N * 4, stream);
    {
        int blocks = (E + 255) / 256;
        count_kernel<<<blocks, 256, 0, stream>>>(dst, cnt, E);
        scan_partial_kernel<<<NB, 256, 0, stream>>>(cnt, blockSums, N);
        scan_offsets_kernel<<<1, 256, 0, stream>>>(blockSums, blockOffs, NB, row_ptr, N);
        scan_fill_kernel<<<NB, 256, 0, stream>>>(cnt, blockOffs, row_ptr, cursor, deg_inv, N);
        fill_kernel<<<blocks, 256, 0, stream>>>(src, dst, cursor, col_idx, E);
    }

    const int aggBlocks = (N + 3) / 4;  // 4 waves/block, 1 wave/node
    dim3 gemmGrid128((N + 63) / 64, NFEAT / 64);
    dim3 gemmGridOut((N + 63) / 64, D_OUT / 64);

    aggregate_kernel<<<aggBlocks, 256, 0, stream>>>(x, row_ptr, col_idx, deg_inv, hA, N);
    gemm_act_kernel<<<gemmGrid128, 256, 0, stream>>>(hA, W1, b1, hB, N, NFEAT, 0);

    aggregate_kernel<<<aggBlocks, 256, 0, stream>>>(hB, row_ptr, col_idx, deg_inv, hA, N);
    gemm_act_kernel<<<gemmGrid128, 256, 0, stream>>>(hA, W2, b2, hB, N, NFEAT, 0);

    aggregate_kernel<<<aggBlocks, 256, 0, stream>>>(hB, row_ptr, col_idx, deg_inv, hA, N);
    gemm_act_kernel<<<gemmGridOut, 256, 0, stream>>>(hA, W3, b3, out, N, D_OUT, 1);
}

// Round 3
// 433.294 us; speedup vs baseline: 1.4721x; 1.1686x over previous
//
#include <hip/hip_runtime.h>
#include <hip/hip_bf16.h>
#include <math.h>

// ---------------------------------------------------------------------------
// GraphSAGE (gcn aggregator) x3 layers.
// R3: gather in bf16 (half traffic); layer-3 reordered GEMM-then-aggregate
//     (64-dim bf16 gather = 4x less traffic), bias+sigmoid fused into agg.
//     GEMM compute + accumulation stays fp32.
// ---------------------------------------------------------------------------

#define NFEAT 128
#define SCAN_CHUNK 1024

__device__ __forceinline__ unsigned short f2bf(float f) {  // RTNE fp32->bf16
    unsigned u = __float_as_uint(f);
    u += 0x7fffu + ((u >> 16) & 1u);
    return (unsigned short)(u >> 16);
}
__device__ __forceinline__ float bflo(unsigned u) { return __uint_as_float(u << 16); }
__device__ __forceinline__ float bfhi(unsigned u) { return __uint_as_float(u & 0xffff0000u); }

// ---- CSR build ------------------------------------------------------------

__global__ void count_kernel(const int* __restrict__ dst, int* __restrict__ cnt, int E) {
    int e = blockIdx.x * blockDim.x + threadIdx.x;
    if (e < E) atomicAdd(&cnt[dst[e]], 1);
}

__global__ __launch_bounds__(256) void scan_partial_kernel(const int* __restrict__ cnt,
                                                           int* __restrict__ blockSums, int N) {
    __shared__ int red[256];
    const int t = threadIdx.x;
    const int idx = blockIdx.x * SCAN_CHUNK + t * 4;
    int s = 0;
#pragma unroll
    for (int j = 0; j < 4; ++j)
        if (idx + j < N) s += cnt[idx + j];
    red[t] = s;
    __syncthreads();
    for (int off = 128; off > 0; off >>= 1) {
        if (t < off) red[t] += red[t + off];
        __syncthreads();
    }
    if (t == 0) blockSums[blockIdx.x] = red[0];
}

__global__ __launch_bounds__(256) void scan_offsets_kernel(const int* __restrict__ blockSums,
                                                           int* __restrict__ blockOffs,
                                                           int nb, int* __restrict__ row_ptr, int N) {
    __shared__ int red[256];
    const int t = threadIdx.x;
    int v = (t < nb) ? blockSums[t] : 0;
    red[t] = v;
    __syncthreads();
    for (int off = 1; off < 256; off <<= 1) {
        int w = (t >= off) ? red[t - off] : 0;
        __syncthreads();
        red[t] += w;
        __syncthreads();
    }
    if (t < nb) blockOffs[t] = (t == 0) ? 0 : red[t - 1];
    if (t == 255) row_ptr[N] = red[255];
}

__global__ __launch_bounds__(256) void scan_fill_kernel(const int* __restrict__ cnt,
                                                        const int* __restrict__ blockOffs,
                                                        int* __restrict__ row_ptr,
                                                        int* __restrict__ cursor,
                                                        float* __restrict__ deg_inv, int N) {
    __shared__ int red[256];
    const int t = threadIdx.x;
    const int idx = blockIdx.x * SCAN_CHUNK + t * 4;
    int c[4];
    int s = 0;
#pragma unroll
    for (int j = 0; j < 4; ++j) {
        c[j] = (idx + j < N) ? cnt[idx + j] : 0;
        s += c[j];
    }
    red[t] = s;
    __syncthreads();
    for (int off = 1; off < 256; off <<= 1) {
        int w = (t >= off) ? red[t - off] : 0;
        __syncthreads();
        red[t] += w;
        __syncthreads();
    }
    int run = ((t == 0) ? 0 : red[t - 1]) + blockOffs[blockIdx.x];
#pragma unroll
    for (int j = 0; j < 4; ++j) {
        if (idx + j < N) {
            row_ptr[idx + j] = run;
            cursor[idx + j]  = run;
            deg_inv[idx + j] = 1.0f / (float)(c[j] + 1);
            run += c[j];
        }
    }
}

__global__ void fill_kernel(const int* __restrict__ src, const int* __restrict__ dst,
                            int* __restrict__ cursor, int* __restrict__ col_idx, int E) {
    int e = blockIdx.x * blockDim.x + threadIdx.x;
    if (e < E) {
        int p = atomicAdd(&cursor[dst[e]], 1);
        col_idx[p] = src[e];
    }
}

// ---- fp32 -> bf16 convert (for the layer-1 gather source) -----------------

__global__ __launch_bounds__(256) void cvt_bf16_kernel(const float* __restrict__ in,
                                                       ushort* __restrict__ outb, int n4) {
    int i = blockIdx.x * blockDim.x + threadIdx.x;
    if (i < n4) {
        float4 f = *(const float4*)(in + (size_t)i * 4);
        ushort4 u = make_ushort4(f2bf(f.x), f2bf(f.y), f2bf(f.z), f2bf(f.w));
        *(ushort4*)(outb + (size_t)i * 4) = u;
    }
}

// ---- Aggregation (128 feats, bf16 gather): one wave per node --------------
// lane i loads uint = feats [2i,2i+1]; 64 lanes x 4 B = 256 B per row.

__global__ __launch_bounds__(256) void agg128_bf16_kernel(const ushort* __restrict__ Xb,
                                                          const int* __restrict__ row_ptr,
                                                          const int* __restrict__ col_idx,
                                                          const float* __restrict__ deg_inv,
                                                          float* __restrict__ H, int N) {
    const int wave = blockIdx.x * (blockDim.x >> 6) + (threadIdx.x >> 6);
    const int lane = threadIdx.x & 63;
    if (wave >= N) return;
    const int v   = wave;
    const int beg = row_ptr[v];
    const int end = row_ptr[v + 1];
    const unsigned* Xu = (const unsigned*)Xb;  // row stride 64 uints

    float2 acc0 = make_float2(0.f, 0.f);
    float2 acc1 = make_float2(0.f, 0.f);
    int e = beg;
    for (; e + 1 < end; e += 2) {
        int s0 = col_idx[e];
        int s1 = col_idx[e + 1];
        unsigned u0 = Xu[(size_t)s0 * 64 + lane];
        unsigned u1 = Xu[(size_t)s1 * 64 + lane];
        acc0.x += bflo(u0); acc0.y += bfhi(u0);
        acc1.x += bflo(u1); acc1.y += bfhi(u1);
    }
    if (e < end) {
        unsigned u0 = Xu[(size_t)col_idx[e] * 64 + lane];
        acc0.x += bflo(u0); acc0.y += bfhi(u0);
    }
    unsigned us = Xu[(size_t)v * 64 + lane];
    float inv = deg_inv[v];
    float2 r;
    r.x = (acc0.x + acc1.x + bflo(us)) * inv;
    r.y = (acc0.y + acc1.y + bfhi(us)) * inv;
    *(float2*)(H + (size_t)v * NFEAT + lane * 2) = r;
}

// ---- Final aggregation (64 feats, bf16 gather) + bias + sigmoid -----------
// Half-wave scheme: lanes [0..31] process even edges, [32..63] odd edges,
// each half covers all 64 feats (32 lanes x uint). Cross-half shfl reduce.

__global__ __launch_bounds__(256) void agg64_sigmoid_kernel(const ushort* __restrict__ Gb,
                                                            const int* __restrict__ row_ptr,
                                                            const int* __restrict__ col_idx,
                                                            const float* __restrict__ deg_inv,
                                                            const float* __restrict__ bias,
                                                            float* __restrict__ out, int N) {
    const int wave = blockIdx.x * (blockDim.x >> 6) + (threadIdx.x >> 6);
    const int lane = threadIdx.x & 63;
    if (wave >= N) return;
    const int v    = wave;
    const int half = lane >> 5;
    const int hl   = lane & 31;
    const int beg  = row_ptr[v];
    const int end  = row_ptr[v + 1];
    const unsigned* Gu = (const unsigned*)Gb;  // row stride 32 uints

    float2 acc = make_float2(0.f, 0.f);
    for (int e = beg + half; e < end; e += 2) {
        unsigned u = Gu[(size_t)col_idx[e] * 32 + hl];
        acc.x += bflo(u); acc.y += bfhi(u);
    }
    acc.x += __shfl_xor(acc.x, 32, 64);
    acc.y += __shfl_xor(acc.y, 32, 64);

    unsigned us = Gu[(size_t)v * 32 + hl];
    float inv = deg_inv[v];
    float r0 = (acc.x + bflo(us)) * inv + bias[hl * 2 + 0];
    float r1 = (acc.y + bfhi(us)) * inv + bias[hl * 2 + 1];
    r0 = 1.0f / (1.0f + __expf(-r0));
    r1 = 1.0f / (1.0f + __expf(-r1));
    if (half == 0)
        *(float2*)(out + (size_t)v * 64 + hl * 2) = make_float2(r0, r1);
}

// ---- GEMM: act(H[N,128] @ W[OUT,128]^T + b) -> fp32 or bf16 ---------------
// 64x64 tile, 4x4 microtile. relu: 1 = relu, 0 = none. bias may be null.

__global__ __launch_bounds__(256) void gemm_kernel(const float* __restrict__ H,
                                                   const float* __restrict__ W,
                                                   const float* __restrict__ bias,
                                                   float* __restrict__ outF,
                                                   ushort* __restrict__ outB,
                                                   int N, int OUT, int relu) {
    __shared__ float Hs[16][65];
    __shared__ float Ws[16][65];
    const int t    = threadIdx.x;
    const int row0 = blockIdx.x * 64;
    const int col0 = blockIdx.y * 64;
    const int tx   = t & 15;
    const int ty   = t >> 4;
    const int lr   = t >> 2;
    const int kq   = (t & 3) * 4;

    float acc[4][4] = {};

    for (int k0 = 0; k0 < NFEAT; k0 += 16) {
        float4 hv = make_float4(0.f, 0.f, 0.f, 0.f);
        const int gr = row0 + lr;
        if (gr < N) hv = *(const float4*)(H + (size_t)gr * NFEAT + k0 + kq);
        float4 wv = *(const float4*)(W + (size_t)(col0 + lr) * NFEAT + k0 + kq);
        __syncthreads();
        Hs[kq + 0][lr] = hv.x; Hs[kq + 1][lr] = hv.y; Hs[kq + 2][lr] = hv.z; Hs[kq + 3][lr] = hv.w;
        Ws[kq + 0][lr] = wv.x; Ws[kq + 1][lr] = wv.y; Ws[kq + 2][lr] = wv.z; Ws[kq + 3][lr] = wv.w;
        __syncthreads();
#pragma unroll
        for (int kk = 0; kk < 16; ++kk) {
            float4 a = *(const float4*)&Hs[kk][ty * 4];
            float4 b = *(const float4*)&Ws[kk][tx * 4];
            float av[4] = {a.x, a.y, a.z, a.w};
            float bv[4] = {b.x, b.y, b.z, b.w};
#pragma unroll
            for (int i = 0; i < 4; ++i)
#pragma unroll
                for (int j = 0; j < 4; ++j) acc[i][j] += av[i] * bv[j];
        }
    }

    float bv[4] = {0.f, 0.f, 0.f, 0.f};
    if (bias) {
#pragma unroll
        for (int j = 0; j < 4; ++j) bv[j] = bias[col0 + tx * 4 + j];
    }
#pragma unroll
    for (int i = 0; i < 4; ++i) {
        int r = row0 + ty * 4 + i;
        if (r >= N) break;
        float v0 = acc[i][0] + bv[0];
        float v1 = acc[i][1] + bv[1];
        float v2 = acc[i][2] + bv[2];
        float v3 = acc[i][3] + bv[3];
        if (relu) {
            v0 = fmaxf(v0, 0.f); v1 = fmaxf(v1, 0.f);
            v2 = fmaxf(v2, 0.f); v3 = fmaxf(v3, 0.f);
        }
        size_t base = (size_t)r * OUT + col0 + tx * 4;
        if (outB) {
            *(ushort4*)(outB + base) = make_ushort4(f2bf(v0), f2bf(v1), f2bf(v2), f2bf(v3));
        } else {
            *(float4*)(outF + base) = make_float4(v0, v1, v2, v3);
        }
    }
}

// ---------------------------------------------------------------------------

static inline size_t align256(size_t x) { return (x + 255) & ~(size_t)255; }

extern "C" void kernel_launch(void* const* d_in, const int* in_sizes, int n_in,
                              void* d_out, int out_size, void* d_ws, size_t ws_size,
                              hipStream_t stream) {
    const float* x   = (const float*)d_in[0];
    const int*   src = (const int*)d_in[1];
    const int*   dst = (const int*)d_in[2];
    const float* W1  = (const float*)d_in[3];
    const float* b1  = (const float*)d_in[4];
    const float* W2  = (const float*)d_in[5];
    const float* b2  = (const float*)d_in[6];
    const float* W3  = (const float*)d_in[7];
    const float* b3  = (const float*)d_in[8];
    float*       out = (float*)d_out;

    const int N = in_sizes[0] / NFEAT;     // 50000
    const int E = in_sizes[1];             // 800000
    const int D_OUT = in_sizes[7] / NFEAT; // 64
    const int NB = (N + SCAN_CHUNK - 1) / SCAN_CHUNK;

    // workspace carve (with aliasing):
    //   region: [ xbf (N*128 bf16) | h1bf (N*128 bf16) ]  ==  h2f (N*128 fp32)
    //   hA (N*128 fp32) also reused as gbf (N*64 bf16) after GEMM2.
    char* ws = (char*)d_ws;
    int* cnt       = (int*)ws;  ws += align256((size_t)N * 4);
    int* row_ptr   = (int*)ws;  ws += align256((size_t)(N + 1) * 4);
    int* cursor    = (int*)ws;  ws += align256((size_t)N * 4);
    int* col_idx   = (int*)ws;  ws += align256((size_t)E * 4);
    float* deg_inv = (float*)ws; ws += align256((size_t)N * 4);
    int* blockSums = (int*)ws;  ws += align256((size_t)NB * 4);
    int* blockOffs = (int*)ws;  ws += align256((size_t)NB * 4);
    float* hA      = (float*)ws; ws += align256((size_t)N * NFEAT * 4);
    char* region   = ws;         ws += align256((size_t)N * NFEAT * 4);
    ushort* xbf  = (ushort*)region;
    ushort* h1bf = xbf + (size_t)N * NFEAT;
    float*  h2f  = (float*)region;
    ushort* gbf  = (ushort*)hA;

    // ---- CSR build ----
    hipMemsetAsync(cnt, 0, (size_t)N * 4, stream);
    {
        int blocks = (E + 255) / 256;
        count_kernel<<<blocks, 256, 0, stream>>>(dst, cnt, E);
        scan_partial_kernel<<<NB, 256, 0, stream>>>(cnt, blockSums, N);
        scan_offsets_kernel<<<1, 256, 0, stream>>>(blockSums, blockOffs, NB, row_ptr, N);
        scan_fill_kernel<<<NB, 256, 0, stream>>>(cnt, blockOffs, row_ptr, cursor, deg_inv, N);
        fill_kernel<<<blocks, 256, 0, stream>>>(src, dst, cursor, col_idx, E);
    }

    const int n4 = N * NFEAT / 4;
    cvt_bf16_kernel<<<(n4 + 255) / 256, 256, 0, stream>>>(x, xbf, n4);

    const int aggBlocks = (N + 3) / 4;  // 4 waves/block, 1 wave/node
    dim3 gemmGrid128((N + 63) / 64, NFEAT / 64);
    dim3 gemmGrid64((N + 63) / 64, D_OUT / 64);

    // layer 1
    agg128_bf16_kernel<<<aggBlocks, 256, 0, stream>>>(xbf, row_ptr, col_idx, deg_inv, hA, N);
    gemm_kernel<<<gemmGrid128, 256, 0, stream>>>(hA, W1, b1, nullptr, h1bf, N, NFEAT, 1);
    // layer 2
    agg128_bf16_kernel<<<aggBlocks, 256, 0, stream>>>(h1bf, row_ptr, col_idx, deg_inv, hA, N);
    gemm_kernel<<<gemmGrid128, 256, 0, stream>>>(hA, W2, b2, h2f, nullptr, N, NFEAT, 1);
    // layer 3 (reordered): g = h2 @ W3^T, then aggregate + bias + sigmoid
    gemm_kernel<<<gemmGrid64, 256, 0, stream>>>(h2f, W3, nullptr, nullptr, gbf, N, D_OUT, 0);
    agg64_sigmoid_kernel<<<aggBlocks, 256, 0, stream>>>(gbf, row_ptr, col_idx, deg_inv, b3, out, N);
}

// Round 4
// 352.685 us; speedup vs baseline: 1.8086x; 1.2286x over previous
//
#include <hip/hip_runtime.h>
#include <hip/hip_bf16.h>
#include <math.h>

// ---------------------------------------------------------------------------
// GraphSAGE (gcn aggregator) x3 layers.
// R4: CSR build rewritten as 2-level LDS multisplit partition (coalesced
//     writes; fill_kernel's 51.6 MB scattered WRITE_SIZE eliminated).
//     agg128 reworked: half-wave uint2 gather, 4 rows in flight.
// ---------------------------------------------------------------------------

#define NFEAT 128
#define BSH   7                 // bucket shift: 128 nodes per bucket
#define NBUKP 512               // padded bucket count (actual 391)
#define EPB   2048              // edges per block in partition passes
#define BCAP  3072              // max edges per bucket handled in LDS

__device__ __forceinline__ unsigned short f2bf(float f) {  // RTNE fp32->bf16
    unsigned u = __float_as_uint(f);
    u += 0x7fffu + ((u >> 16) & 1u);
    return (unsigned short)(u >> 16);
}
__device__ __forceinline__ float bflo(unsigned u) { return __uint_as_float(u << 16); }
__device__ __forceinline__ float bfhi(unsigned u) { return __uint_as_float(u & 0xffff0000u); }

// ---- Pass A1: coarse bucket histogram -------------------------------------

__global__ __launch_bounds__(256) void partA1_count(const int* __restrict__ dst,
                                                    int* __restrict__ bucketCnt, int E) {
    __shared__ int hist[NBUKP];
    const int t = threadIdx.x;
    hist[t] = 0; hist[t + 256] = 0;
    __syncthreads();
    const int base = blockIdx.x * EPB;
#pragma unroll
    for (int j = 0; j < EPB / 256; ++j) {
        int e = base + t + 256 * j;
        if (e < E) atomicAdd(&hist[dst[e] >> BSH], 1);
    }
    __syncthreads();
    for (int b = t; b < NBUKP; b += 256) {
        int h = hist[b];
        if (h > 0) atomicAdd(&bucketCnt[b], h);
    }
}

// ---- Pass A2: scan bucket counts -> bucketOff, bucketCursor ---------------

__global__ __launch_bounds__(512) void partA2_scan(const int* __restrict__ bucketCnt,
                                                   int* __restrict__ bucketOff,
                                                   int* __restrict__ bucketCursor,
                                                   int* __restrict__ row_ptr, int N, int E) {
    __shared__ int sc[NBUKP];
    const int t = threadIdx.x;
    sc[t] = bucketCnt[t];
    __syncthreads();
    for (int off = 1; off < NBUKP; off <<= 1) {
        int v = (t >= off) ? sc[t - off] : 0;
        __syncthreads();
        sc[t] += v;
        __syncthreads();
    }
    int excl = sc[t] - bucketCnt[t];
    bucketOff[t] = excl;
    bucketCursor[t] = excl;
    if (t == 0) row_ptr[N] = E;
}

// ---- Pass A3: LDS-staged scatter of (src,dst) pairs grouped by bucket -----

__global__ __launch_bounds__(256) void partA3_scatter(const int* __restrict__ src,
                                                      const int* __restrict__ dst,
                                                      int* __restrict__ bucketCursor,
                                                      unsigned long long* __restrict__ pairs,
                                                      int E) {
    __shared__ int hist[NBUKP];
    __shared__ int sc[NBUKP];     // becomes exclusive local prefix
    __shared__ int lcur[NBUKP];
    __shared__ int lbase[NBUKP];
    __shared__ unsigned long long stage[EPB];
    __shared__ int destIdx[EPB];
    __shared__ int nLocalSh;

    const int t = threadIdx.x;
    hist[t] = 0; hist[t + 256] = 0;
    lcur[t] = 0; lcur[t + 256] = 0;
    __syncthreads();

    const int base = blockIdx.x * EPB;
    int bb[EPB / 256];
    unsigned long long pr[EPB / 256];
#pragma unroll
    for (int j = 0; j < EPB / 256; ++j) {
        int e = base + t + 256 * j;
        bb[j] = -1;
        if (e < E) {
            int s = src[e], d = dst[e];
            int b = d >> BSH;
            bb[j] = b;
            pr[j] = ((unsigned long long)(unsigned)d << 32) | (unsigned)s;
            atomicAdd(&hist[b], 1);
        }
    }
    __syncthreads();
    // inclusive scan of hist[512] with 256 threads (2 elems/thread)
    sc[t] = hist[t]; sc[t + 256] = hist[t + 256];
    __syncthreads();
    for (int off = 1; off < NBUKP; off <<= 1) {
        int v0 = (t >= off) ? sc[t - off] : 0;
        int v1 = (t + 256 >= off) ? sc[t + 256 - off] : 0;
        __syncthreads();
        sc[t] += v0; sc[t + 256] += v1;
        __syncthreads();
    }
    if (t == 255) nLocalSh = sc[NBUKP - 1];
    // convert to exclusive (each thread touches only its own 2 entries)
    sc[t] -= hist[t]; sc[t + 256] -= hist[t + 256];
    // reserve global ranges
    for (int b = t; b < NBUKP; b += 256) {
        int h = hist[b];
        if (h > 0) lbase[b] = atomicAdd(&bucketCursor[b], h);
    }
    __syncthreads();
    // scatter into LDS stage ordered by bucket
#pragma unroll
    for (int j = 0; j < EPB / 256; ++j) {
        int b = bb[j];
        if (b >= 0) {
            int slot = atomicAdd(&lcur[b], 1);
            int spos = sc[b] + slot;
            stage[spos] = pr[j];
            destIdx[spos] = lbase[b] + slot;
        }
    }
    __syncthreads();
    const int nLocal = nLocalSh;
#pragma unroll
    for (int j = 0; j < EPB / 256; ++j) {
        int i = t + 256 * j;
        if (i < nLocal) pairs[destIdx[i]] = stage[i];
    }
}

// ---- Pass B: per-bucket sort by dst, emit row_ptr/deg_inv/col_idx ---------

__global__ __launch_bounds__(256) void partB_build(const unsigned long long* __restrict__ pairs,
                                                   const int* __restrict__ bucketOff,
                                                   const int* __restrict__ bucketCnt,
                                                   int* __restrict__ row_ptr,
                                                   float* __restrict__ deg_inv,
                                                   int* __restrict__ col_idx, int N) {
    __shared__ unsigned long long pairsL[BCAP];
    __shared__ int srcS[BCAP];
    __shared__ int nhist[128];
    __shared__ int npref[128];
    __shared__ int ncur[128];

    const int t = threadIdx.x;
    const int b = blockIdx.x;
    const int nodeBase = b << BSH;
    const int eBeg = bucketOff[b];
    const int eCnt = bucketCnt[b];

    if (t < 128) { nhist[t] = 0; ncur[t] = 0; }
    __syncthreads();

    if (eCnt <= BCAP) {
        for (int i = t; i < eCnt; i += 256) {
            unsigned long long p = pairs[eBeg + i];
            pairsL[i] = p;
            atomicAdd(&nhist[(int)(p >> 32) - nodeBase], 1);
        }
        __syncthreads();
        // exclusive scan of nhist[128]
        if (t < 128) npref[t] = nhist[t];
        __syncthreads();
        for (int off = 1; off < 128; off <<= 1) {
            int v = (t < 128 && t >= off) ? npref[t - off] : 0;
            __syncthreads();
            if (t < 128) npref[t] += v;
            __syncthreads();
        }
        if (t < 128) npref[t] -= nhist[t];  // own entry only
        if (t < 128 && nodeBase + t < N) {
            row_ptr[nodeBase + t] = eBeg + npref[t];
            deg_inv[nodeBase + t] = 1.0f / (float)(nhist[t] + 1);
        }
        __syncthreads();
        for (int i = t; i < eCnt; i += 256) {
            unsigned long long p = pairsL[i];
            int d = (int)(p >> 32) - nodeBase;
            int slot = atomicAdd(&ncur[d], 1);
            srcS[npref[d] + slot] = (int)(unsigned)p;
        }
        __syncthreads();
        for (int i = t; i < eCnt; i += 256) col_idx[eBeg + i] = srcS[i];
    } else {
        // fallback: operate from global (rare/never for this input)
        for (int i = t; i < eCnt; i += 256) {
            unsigned long long p = pairs[eBeg + i];
            atomicAdd(&nhist[(int)(p >> 32) - nodeBase], 1);
        }
        __syncthreads();
        if (t < 128) npref[t] = nhist[t];
        __syncthreads();
        for (int off = 1; off < 128; off <<= 1) {
            int v = (t < 128 && t >= off) ? npref[t - off] : 0;
            __syncthreads();
            if (t < 128) npref[t] += v;
            __syncthreads();
        }
        if (t < 128) npref[t] -= nhist[t];
        if (t < 128 && nodeBase + t < N) {
            row_ptr[nodeBase + t] = eBeg + npref[t];
            deg_inv[nodeBase + t] = 1.0f / (float)(nhist[t] + 1);
        }
        __syncthreads();
        for (int i = t; i < eCnt; i += 256) {
            unsigned long long p = pairs[eBeg + i];
            int d = (int)(p >> 32) - nodeBase;
            int slot = atomicAdd(&ncur[d], 1);
            col_idx[eBeg + npref[d] + slot] = (int)(unsigned)p;
        }
    }
}

// ---- fp32 -> bf16 convert -------------------------------------------------

__global__ __launch_bounds__(256) void cvt_bf16_kernel(const float* __restrict__ in,
                                                       ushort* __restrict__ outb, int n4) {
    int i = blockIdx.x * blockDim.x + threadIdx.x;
    if (i < n4) {
        float4 f = *(const float4*)(in + (size_t)i * 4);
        ushort4 u = make_ushort4(f2bf(f.x), f2bf(f.y), f2bf(f.z), f2bf(f.w));
        *(ushort4*)(outb + (size_t)i * 4) = u;
    }
}

// ---- Aggregation (128 feats, bf16): half-wave uint2, 4 rows in flight -----

__global__ __launch_bounds__(256) void agg128_bf16_kernel(const ushort* __restrict__ Xb,
                                                          const int* __restrict__ row_ptr,
                                                          const int* __restrict__ col_idx,
                                                          const float* __restrict__ deg_inv,
                                                          float* __restrict__ H, int N) {
    const int wave = blockIdx.x * (blockDim.x >> 6) + (threadIdx.x >> 6);
    const int lane = threadIdx.x & 63;
    if (wave >= N) return;
    const int v    = wave;
    const int half = lane >> 5;
    const int hl   = lane & 31;
    const int beg  = row_ptr[v];
    const int end  = row_ptr[v + 1];
    const uint2* X2 = (const uint2*)Xb;  // row stride 32 uint2 (= 128 bf16)

    float a0 = 0.f, a1 = 0.f, a2 = 0.f, a3 = 0.f;  // feats 4hl..4hl+3
    float b0 = 0.f, b1 = 0.f, b2 = 0.f, b3 = 0.f;
    int e = beg + half;
    for (; e + 2 < end; e += 4) {
        uint2 u = X2[(size_t)col_idx[e] * 32 + hl];
        uint2 w = X2[(size_t)col_idx[e + 2] * 32 + hl];
        a0 += bflo(u.x); a1 += bfhi(u.x); a2 += bflo(u.y); a3 += bfhi(u.y);
        b0 += bflo(w.x); b1 += bfhi(w.x); b2 += bflo(w.y); b3 += bfhi(w.y);
    }
    if (e < end) {
        uint2 u = X2[(size_t)col_idx[e] * 32 + hl];
        a0 += bflo(u.x); a1 += bfhi(u.x); a2 += bflo(u.y); a3 += bfhi(u.y);
    }
    a0 += b0; a1 += b1; a2 += b2; a3 += b3;
    // cross-half reduce
    a0 += __shfl_xor(a0, 32, 64);
    a1 += __shfl_xor(a1, 32, 64);
    a2 += __shfl_xor(a2, 32, 64);
    a3 += __shfl_xor(a3, 32, 64);
    if (half == 0) {
        uint2 us = X2[(size_t)v * 32 + hl];
        float inv = deg_inv[v];
        float4 r;
        r.x = (a0 + bflo(us.x)) * inv;
        r.y = (a1 + bfhi(us.x)) * inv;
        r.z = (a2 + bflo(us.y)) * inv;
        r.w = (a3 + bfhi(us.y)) * inv;
        *(float4*)(H + (size_t)v * NFEAT + hl * 4) = r;
    }
}

// ---- Final aggregation (64 feats, bf16) + bias + sigmoid ------------------

__global__ __launch_bounds__(256) void agg64_sigmoid_kernel(const ushort* __restrict__ Gb,
                                                            const int* __restrict__ row_ptr,
                                                            const int* __restrict__ col_idx,
                                                            const float* __restrict__ deg_inv,
                                                            const float* __restrict__ bias,
                                                            float* __restrict__ out, int N) {
    const int wave = blockIdx.x * (blockDim.x >> 6) + (threadIdx.x >> 6);
    const int lane = threadIdx.x & 63;
    if (wave >= N) return;
    const int v    = wave;
    const int half = lane >> 5;
    const int hl   = lane & 31;
    const int beg  = row_ptr[v];
    const int end  = row_ptr[v + 1];
    const unsigned* Gu = (const unsigned*)Gb;  // row stride 32 uints

    float2 acc = make_float2(0.f, 0.f);
    for (int e = beg + half; e < end; e += 2) {
        unsigned u = Gu[(size_t)col_idx[e] * 32 + hl];
        acc.x += bflo(u); acc.y += bfhi(u);
    }
    acc.x += __shfl_xor(acc.x, 32, 64);
    acc.y += __shfl_xor(acc.y, 32, 64);

    if (half == 0) {
        unsigned us = Gu[(size_t)v * 32 + hl];
        float inv = deg_inv[v];
        float r0 = (acc.x + bflo(us)) * inv + bias[hl * 2 + 0];
        float r1 = (acc.y + bfhi(us)) * inv + bias[hl * 2 + 1];
        r0 = 1.0f / (1.0f + __expf(-r0));
        r1 = 1.0f / (1.0f + __expf(-r1));
        *(float2*)(out + (size_t)v * 64 + hl * 2) = make_float2(r0, r1);
    }
}

// ---- GEMM: act(H[N,128] @ W[OUT,128]^T + b) -> fp32 or bf16 ---------------

__global__ __launch_bounds__(256) void gemm_kernel(const float* __restrict__ H,
                                                   const float* __restrict__ W,
                                                   const float* __restrict__ bias,
                                                   float* __restrict__ outF,
                                                   ushort* __restrict__ outB,
                                                   int N, int OUT, int relu) {
    __shared__ float Hs[16][65];
    __shared__ float Ws[16][65];
    const int t    = threadIdx.x;
    const int row0 = blockIdx.x * 64;
    const int col0 = blockIdx.y * 64;
    const int tx   = t & 15;
    const int ty   = t >> 4;
    const int lr   = t >> 2;
    const int kq   = (t & 3) * 4;

    float acc[4][4] = {};

    for (int k0 = 0; k0 < NFEAT; k0 += 16) {
        float4 hv = make_float4(0.f, 0.f, 0.f, 0.f);
        const int gr = row0 + lr;
        if (gr < N) hv = *(const float4*)(H + (size_t)gr * NFEAT + k0 + kq);
        float4 wv = *(const float4*)(W + (size_t)(col0 + lr) * NFEAT + k0 + kq);
        __syncthreads();
        Hs[kq + 0][lr] = hv.x; Hs[kq + 1][lr] = hv.y; Hs[kq + 2][lr] = hv.z; Hs[kq + 3][lr] = hv.w;
        Ws[kq + 0][lr] = wv.x; Ws[kq + 1][lr] = wv.y; Ws[kq + 2][lr] = wv.z; Ws[kq + 3][lr] = wv.w;
        __syncthreads();
#pragma unroll
        for (int kk = 0; kk < 16; ++kk) {
            float4 a = *(const float4*)&Hs[kk][ty * 4];
            float4 b = *(const float4*)&Ws[kk][tx * 4];
            float av[4] = {a.x, a.y, a.z, a.w};
            float bv[4] = {b.x, b.y, b.z, b.w};
#pragma unroll
            for (int i = 0; i < 4; ++i)
#pragma unroll
                for (int j = 0; j < 4; ++j) acc[i][j] += av[i] * bv[j];
        }
    }

    float bv[4] = {0.f, 0.f, 0.f, 0.f};
    if (bias) {
#pragma unroll
        for (int j = 0; j < 4; ++j) bv[j] = bias[col0 + tx * 4 + j];
    }
#pragma unroll
    for (int i = 0; i < 4; ++i) {
        int r = row0 + ty * 4 + i;
        if (r >= N) break;
        float v0 = acc[i][0] + bv[0];
        float v1 = acc[i][1] + bv[1];
        float v2 = acc[i][2] + bv[2];
        float v3 = acc[i][3] + bv[3];
        if (relu) {
            v0 = fmaxf(v0, 0.f); v1 = fmaxf(v1, 0.f);
            v2 = fmaxf(v2, 0.f); v3 = fmaxf(v3, 0.f);
        }
        size_t base = (size_t)r * OUT + col0 + tx * 4;
        if (outB) {
            *(ushort4*)(outB + base) = make_ushort4(f2bf(v0), f2bf(v1), f2bf(v2), f2bf(v3));
        } else {
            *(float4*)(outF + base) = make_float4(v0, v1, v2, v3);
        }
    }
}

// ---------------------------------------------------------------------------

static inline size_t align256(size_t x) { return (x + 255) & ~(size_t)255; }

extern "C" void kernel_launch(void* const* d_in, const int* in_sizes, int n_in,
                              void* d_out, int out_size, void* d_ws, size_t ws_size,
                              hipStream_t stream) {
    const float* x   = (const float*)d_in[0];
    const int*   src = (const int*)d_in[1];
    const int*   dst = (const int*)d_in[2];
    const float* W1  = (const float*)d_in[3];
    const float* b1  = (const float*)d_in[4];
    const float* W2  = (const float*)d_in[5];
    const float* b2  = (const float*)d_in[6];
    const float* W3  = (const float*)d_in[7];
    const float* b3  = (const float*)d_in[8];
    float*       out = (float*)d_out;

    const int N = in_sizes[0] / NFEAT;     // 50000
    const int E = in_sizes[1];             // 800000
    const int D_OUT = in_sizes[7] / NFEAT; // 64
    const int NBUK = (N + (1 << BSH) - 1) >> BSH;   // 391 (fits NBUKP=512)
    const int PBLK = (E + EPB - 1) / EPB;           // 391 partition blocks

    // workspace carve (pairs aliased onto region: dead before cvt writes xbf)
    char* ws = (char*)d_ws;
    int* row_ptr      = (int*)ws;  ws += align256((size_t)(N + 1) * 4);
    int* col_idx      = (int*)ws;  ws += align256((size_t)E * 4);
    float* deg_inv    = (float*)ws; ws += align256((size_t)N * 4);
    int* bucketCnt    = (int*)ws;  ws += align256((size_t)NBUKP * 4);
    int* bucketOff    = (int*)ws;  ws += align256((size_t)NBUKP * 4);
    int* bucketCursor = (int*)ws;  ws += align256((size_t)NBUKP * 4);
    float* hA         = (float*)ws; ws += align256((size_t)N * NFEAT * 4);
    char* region      = ws;         ws += align256((size_t)N * NFEAT * 4);
    ushort* xbf  = (ushort*)region;
    ushort* h1bf = xbf + (size_t)N * NFEAT;
    float*  h2f  = (float*)region;
    ushort* gbf  = (ushort*)hA;
    unsigned long long* pairs = (unsigned long long*)region;  // 6.4 MB, CSR-build only

    // ---- CSR build via 2-level partition ----
    hipMemsetAsync(bucketCnt, 0, (size_t)NBUKP * 4, stream);
    partA1_count<<<PBLK, 256, 0, stream>>>(dst, bucketCnt, E);
    partA2_scan<<<1, NBUKP, 0, stream>>>(bucketCnt, bucketOff, bucketCursor, row_ptr, N, E);
    partA3_scatter<<<PBLK, 256, 0, stream>>>(src, dst, bucketCursor, pairs, E);
    partB_build<<<NBUK, 256, 0, stream>>>(pairs, bucketOff, bucketCnt, row_ptr, deg_inv, col_idx, N);

    const int n4 = N * NFEAT / 4;
    cvt_bf16_kernel<<<(n4 + 255) / 256, 256, 0, stream>>>(x, xbf, n4);

    const int aggBlocks = (N + 3) / 4;  // 4 waves/block, 1 wave/node
    dim3 gemmGrid128((N + 63) / 64, NFEAT / 64);
    dim3 gemmGrid64((N + 63) / 64, D_OUT / 64);

    // layer 1
    agg128_bf16_kernel<<<aggBlocks, 256, 0, stream>>>(xbf, row_ptr, col_idx, deg_inv, hA, N);
    gemm_kernel<<<gemmGrid128, 256, 0, stream>>>(hA, W1, b1, nullptr, h1bf, N, NFEAT, 1);
    // layer 2
    agg128_bf16_kernel<<<aggBlocks, 256, 0, stream>>>(h1bf, row_ptr, col_idx, deg_inv, hA, N);
    gemm_kernel<<<gemmGrid128, 256, 0, stream>>>(hA, W2, b2, h2f, nullptr, N, NFEAT, 1);
    // layer 3 (reordered): g = h2 @ W3^T, then aggregate + bias + sigmoid
    gemm_kernel<<<gemmGrid64, 256, 0, stream>>>(h2f, W3, nullptr, nullptr, gbf, N, D_OUT, 0);
    agg64_sigmoid_kernel<<<aggBlocks, 256, 0, stream>>>(gbf, row_ptr, col_idx, deg_inv, b3, out, N);
}

// Round 5
// 315.084 us; speedup vs baseline: 2.0244x; 1.1193x over previous
//
#include <hip/hip_runtime.h>
#include <hip/hip_bf16.h>
#include <math.h>

// ---------------------------------------------------------------------------
// GraphSAGE (gcn aggregator) x3 layers.
// R5: aggregations restructured for memory-level parallelism:
//     - col_idx preloaded into registers (one coalesced load), edge sources
//       broadcast via __shfl -> gather addresses are pure VALU.
//     - 4 independent gather streams in flight (was 1-2).
//     - agg64: two nodes per wave (one per half), no cross-half reduce.
//     - agg outputs bf16; GEMM reads bf16 H (halves agg writes + GEMM fetch).
// ---------------------------------------------------------------------------

#define NFEAT 128
#define BSH   7                 // bucket shift: 128 nodes per bucket
#define NBUKP 512               // padded bucket count (actual 391)
#define EPB   2048              // edges per block in partition passes
#define BCAP  3072              // max edges per bucket handled in LDS

__device__ __forceinline__ unsigned short f2bf(float f) {  // RTNE fp32->bf16
    unsigned u = __float_as_uint(f);
    u += 0x7fffu + ((u >> 16) & 1u);
    return (unsigned short)(u >> 16);
}
__device__ __forceinline__ float bflo(unsigned u) { return __uint_as_float(u << 16); }
__device__ __forceinline__ float bfhi(unsigned u) { return __uint_as_float(u & 0xffff0000u); }
__device__ __forceinline__ float bf2f(unsigned short u) { return __uint_as_float((unsigned)u << 16); }

// ---- Pass A1: coarse bucket histogram -------------------------------------

__global__ __launch_bounds__(256) void partA1_count(const int* __restrict__ dst,
                                                    int* __restrict__ bucketCnt, int E) {
    __shared__ int hist[NBUKP];
    const int t = threadIdx.x;
    hist[t] = 0; hist[t + 256] = 0;
    __syncthreads();
    const int base = blockIdx.x * EPB;
#pragma unroll
    for (int j = 0; j < EPB / 256; ++j) {
        int e = base + t + 256 * j;
        if (e < E) atomicAdd(&hist[dst[e] >> BSH], 1);
    }
    __syncthreads();
    for (int b = t; b < NBUKP; b += 256) {
        int h = hist[b];
        if (h > 0) atomicAdd(&bucketCnt[b], h);
    }
}

// ---- Pass A2: scan bucket counts -> bucketOff, bucketCursor ---------------

__global__ __launch_bounds__(512) void partA2_scan(const int* __restrict__ bucketCnt,
                                                   int* __restrict__ bucketOff,
                                                   int* __restrict__ bucketCursor,
                                                   int* __restrict__ row_ptr, int N, int E) {
    __shared__ int sc[NBUKP];
    const int t = threadIdx.x;
    sc[t] = bucketCnt[t];
    __syncthreads();
    for (int off = 1; off < NBUKP; off <<= 1) {
        int v = (t >= off) ? sc[t - off] : 0;
        __syncthreads();
        sc[t] += v;
        __syncthreads();
    }
    int excl = sc[t] - bucketCnt[t];
    bucketOff[t] = excl;
    bucketCursor[t] = excl;
    if (t == 0) row_ptr[N] = E;
}

// ---- Pass A3: LDS-staged scatter of (src,dst) pairs grouped by bucket -----

__global__ __launch_bounds__(256) void partA3_scatter(const int* __restrict__ src,
                                                      const int* __restrict__ dst,
                                                      int* __restrict__ bucketCursor,
                                                      unsigned long long* __restrict__ pairs,
                                                      int E) {
    __shared__ int hist[NBUKP];
    __shared__ int sc[NBUKP];
    __shared__ int lcur[NBUKP];
    __shared__ int lbase[NBUKP];
    __shared__ unsigned long long stage[EPB];
    __shared__ int destIdx[EPB];
    __shared__ int nLocalSh;

    const int t = threadIdx.x;
    hist[t] = 0; hist[t + 256] = 0;
    lcur[t] = 0; lcur[t + 256] = 0;
    __syncthreads();

    const int base = blockIdx.x * EPB;
    int bb[EPB / 256];
    unsigned long long pr[EPB / 256];
#pragma unroll
    for (int j = 0; j < EPB / 256; ++j) {
        int e = base + t + 256 * j;
        bb[j] = -1;
        if (e < E) {
            int s = src[e], d = dst[e];
            int b = d >> BSH;
            bb[j] = b;
            pr[j] = ((unsigned long long)(unsigned)d << 32) | (unsigned)s;
            atomicAdd(&hist[b], 1);
        }
    }
    __syncthreads();
    sc[t] = hist[t]; sc[t + 256] = hist[t + 256];
    __syncthreads();
    for (int off = 1; off < NBUKP; off <<= 1) {
        int v0 = (t >= off) ? sc[t - off] : 0;
        int v1 = (t + 256 >= off) ? sc[t + 256 - off] : 0;
        __syncthreads();
        sc[t] += v0; sc[t + 256] += v1;
        __syncthreads();
    }
    if (t == 255) nLocalSh = sc[NBUKP - 1];
    sc[t] -= hist[t]; sc[t + 256] -= hist[t + 256];
    for (int b = t; b < NBUKP; b += 256) {
        int h = hist[b];
        if (h > 0) lbase[b] = atomicAdd(&bucketCursor[b], h);
    }
    __syncthreads();
#pragma unroll
    for (int j = 0; j < EPB / 256; ++j) {
        int b = bb[j];
        if (b >= 0) {
            int slot = atomicAdd(&lcur[b], 1);
            int spos = sc[b] + slot;
            stage[spos] = pr[j];
            destIdx[spos] = lbase[b] + slot;
        }
    }
    __syncthreads();
    const int nLocal = nLocalSh;
#pragma unroll
    for (int j = 0; j < EPB / 256; ++j) {
        int i = t + 256 * j;
        if (i < nLocal) pairs[destIdx[i]] = stage[i];
    }
}

// ---- Pass B: per-bucket sort by dst, emit row_ptr/deg_inv/col_idx ---------

__global__ __launch_bounds__(256) void partB_build(const unsigned long long* __restrict__ pairs,
                                                   const int* __restrict__ bucketOff,
                                                   const int* __restrict__ bucketCnt,
                                                   int* __restrict__ row_ptr,
                                                   float* __restrict__ deg_inv,
                                                   int* __restrict__ col_idx, int N) {
    __shared__ unsigned long long pairsL[BCAP];
    __shared__ int srcS[BCAP];
    __shared__ int nhist[128];
    __shared__ int npref[128];
    __shared__ int ncur[128];

    const int t = threadIdx.x;
    const int b = blockIdx.x;
    const int nodeBase = b << BSH;
    const int eBeg = bucketOff[b];
    const int eCnt = bucketCnt[b];

    if (t < 128) { nhist[t] = 0; ncur[t] = 0; }
    __syncthreads();

    if (eCnt <= BCAP) {
        for (int i = t; i < eCnt; i += 256) {
            unsigned long long p = pairs[eBeg + i];
            pairsL[i] = p;
            atomicAdd(&nhist[(int)(p >> 32) - nodeBase], 1);
        }
        __syncthreads();
        if (t < 128) npref[t] = nhist[t];
        __syncthreads();
        for (int off = 1; off < 128; off <<= 1) {
            int v = (t < 128 && t >= off) ? npref[t - off] : 0;
            __syncthreads();
            if (t < 128) npref[t] += v;
            __syncthreads();
        }
        if (t < 128) npref[t] -= nhist[t];
        if (t < 128 && nodeBase + t < N) {
            row_ptr[nodeBase + t] = eBeg + npref[t];
            deg_inv[nodeBase + t] = 1.0f / (float)(nhist[t] + 1);
        }
        __syncthreads();
        for (int i = t; i < eCnt; i += 256) {
            unsigned long long p = pairsL[i];
            int d = (int)(p >> 32) - nodeBase;
            int slot = atomicAdd(&ncur[d], 1);
            srcS[npref[d] + slot] = (int)(unsigned)p;
        }
        __syncthreads();
        for (int i = t; i < eCnt; i += 256) col_idx[eBeg + i] = srcS[i];
    } else {
        for (int i = t; i < eCnt; i += 256) {
            unsigned long long p = pairs[eBeg + i];
            atomicAdd(&nhist[(int)(p >> 32) - nodeBase], 1);
        }
        __syncthreads();
        if (t < 128) npref[t] = nhist[t];
        __syncthreads();
        for (int off = 1; off < 128; off <<= 1) {
            int v = (t < 128 && t >= off) ? npref[t - off] : 0;
            __syncthreads();
            if (t < 128) npref[t] += v;
            __syncthreads();
        }
        if (t < 128) npref[t] -= nhist[t];
        if (t < 128 && nodeBase + t < N) {
            row_ptr[nodeBase + t] = eBeg + npref[t];
            deg_inv[nodeBase + t] = 1.0f / (float)(nhist[t] + 1);
        }
        __syncthreads();
        for (int i = t; i < eCnt; i += 256) {
            unsigned long long p = pairs[eBeg + i];
            int d = (int)(p >> 32) - nodeBase;
            int slot = atomicAdd(&ncur[d], 1);
            col_idx[eBeg + npref[d] + slot] = (int)(unsigned)p;
        }
    }
}

// ---- fp32 -> bf16 convert -------------------------------------------------

__global__ __launch_bounds__(256) void cvt_bf16_kernel(const float* __restrict__ in,
                                                       ushort* __restrict__ outb, int n4) {
    int i = blockIdx.x * blockDim.x + threadIdx.x;
    if (i < n4) {
        float4 f = *(const float4*)(in + (size_t)i * 4);
        ushort4 u = make_ushort4(f2bf(f.x), f2bf(f.y), f2bf(f.z), f2bf(f.w));
        *(ushort4*)(outb + (size_t)i * 4) = u;
    }
}

// ---- Aggregation (128 feats, bf16 in/out): 1 node/wave, reg-cidx, MLP=4 ---
// lane holds feats [2*lane, 2*lane+1] (one uint). col_idx[beg+lane] preloaded;
// per-edge source index comes from __shfl broadcast (no memory in addr chain).

__global__ __launch_bounds__(256) void agg128_kernel(const ushort* __restrict__ Xb,
                                                     const int* __restrict__ row_ptr,
                                                     const int* __restrict__ col_idx,
                                                     const float* __restrict__ deg_inv,
                                                     ushort* __restrict__ Hb, int N) {
    const int v    = blockIdx.x * (blockDim.x >> 6) + (threadIdx.x >> 6);
    const int lane = threadIdx.x & 63;
    if (v >= N) return;
    const int beg = row_ptr[v];
    const int end = row_ptr[v + 1];
    const int deg = end - beg;
    const unsigned* Xu = (const unsigned*)Xb;  // row stride 64 uints

    int cidx = 0;
    if (lane < deg) cidx = col_idx[beg + lane];

    float a0 = 0.f, a1 = 0.f, b0 = 0.f, b1 = 0.f;
    float c0 = 0.f, c1 = 0.f, d0 = 0.f, d1 = 0.f;
    const int nfast = deg < 64 ? deg : 64;
    int j = 0;
    for (; j + 3 < nfast; j += 4) {
        int s0 = __shfl(cidx, j + 0, 64);
        int s1 = __shfl(cidx, j + 1, 64);
        int s2 = __shfl(cidx, j + 2, 64);
        int s3 = __shfl(cidx, j + 3, 64);
        unsigned u0 = Xu[(size_t)s0 * 64 + lane];
        unsigned u1 = Xu[(size_t)s1 * 64 + lane];
        unsigned u2 = Xu[(size_t)s2 * 64 + lane];
        unsigned u3 = Xu[(size_t)s3 * 64 + lane];
        a0 += bflo(u0); a1 += bfhi(u0);
        b0 += bflo(u1); b1 += bfhi(u1);
        c0 += bflo(u2); c1 += bfhi(u2);
        d0 += bflo(u3); d1 += bfhi(u3);
    }
    for (; j < nfast; ++j) {
        int s0 = __shfl(cidx, j, 64);
        unsigned u0 = Xu[(size_t)s0 * 64 + lane];
        a0 += bflo(u0); a1 += bfhi(u0);
    }
    for (int e = beg + 64; e < end; ++e) {   // rare: deg > 64
        unsigned u0 = Xu[(size_t)col_idx[e] * 64 + lane];
        a0 += bflo(u0); a1 += bfhi(u0);
    }
    unsigned us = Xu[(size_t)v * 64 + lane];
    float inv = deg_inv[v];
    float r0 = (a0 + b0 + c0 + d0 + bflo(us)) * inv;
    float r1 = (a1 + b1 + c1 + d1 + bfhi(us)) * inv;
    unsigned ru = (unsigned)f2bf(r0) | ((unsigned)f2bf(r1) << 16);
    ((unsigned*)Hb)[(size_t)v * 64 + lane] = ru;
}

// ---- Final aggregation (64 feats, bf16) + bias + sigmoid ------------------
// 2 nodes per wave: half h handles node 2*wp+h; lane hl holds feats [2hl,2hl+1].

__global__ __launch_bounds__(256) void agg64_sigmoid_kernel(const ushort* __restrict__ Gb,
                                                            const int* __restrict__ row_ptr,
                                                            const int* __restrict__ col_idx,
                                                            const float* __restrict__ deg_inv,
                                                            const float* __restrict__ bias,
                                                            float* __restrict__ out, int N) {
    const int wp   = blockIdx.x * (blockDim.x >> 6) + (threadIdx.x >> 6);
    const int lane = threadIdx.x & 63;
    const int half = lane >> 5;
    const int hl   = lane & 31;
    const int v    = wp * 2 + half;
    const bool act = (v < N);

    int beg = 0, end = 0;
    if (act) { beg = row_ptr[v]; end = row_ptr[v + 1]; }
    const int deg = end - beg;
    const unsigned* Gu = (const unsigned*)Gb;  // row stride 32 uints

    int cidx = 0;
    if (hl < deg) cidx = col_idx[beg + hl];

    float a0 = 0.f, a1 = 0.f, b0 = 0.f, b1 = 0.f;
    float c0 = 0.f, c1 = 0.f, d0 = 0.f, d1 = 0.f;
    const int nfast = deg < 32 ? deg : 32;
    int j = 0;
    for (; j + 3 < nfast; j += 4) {
        int s0 = __shfl(cidx, j + 0, 32);
        int s1 = __shfl(cidx, j + 1, 32);
        int s2 = __shfl(cidx, j + 2, 32);
        int s3 = __shfl(cidx, j + 3, 32);
        unsigned u0 = Gu[(size_t)s0 * 32 + hl];
        unsigned u1 = Gu[(size_t)s1 * 32 + hl];
        unsigned u2 = Gu[(size_t)s2 * 32 + hl];
        unsigned u3 = Gu[(size_t)s3 * 32 + hl];
        a0 += bflo(u0); a1 += bfhi(u0);
        b0 += bflo(u1); b1 += bfhi(u1);
        c0 += bflo(u2); c1 += bfhi(u2);
        d0 += bflo(u3); d1 += bfhi(u3);
    }
    for (; j < nfast; ++j) {
        int s0 = __shfl(cidx, j, 32);
        unsigned u0 = Gu[(size_t)s0 * 32 + hl];
        a0 += bflo(u0); a1 += bfhi(u0);
    }
    for (int e = beg + 32; e < end; ++e) {   // rare: deg > 32
        unsigned u0 = Gu[(size_t)col_idx[e] * 32 + hl];
        a0 += bflo(u0); a1 += bfhi(u0);
    }
    if (act) {
        unsigned us = Gu[(size_t)v * 32 + hl];
        float inv = deg_inv[v];
        float r0 = (a0 + b0 + c0 + d0 + bflo(us)) * inv + bias[hl * 2 + 0];
        float r1 = (a1 + b1 + c1 + d1 + bfhi(us)) * inv + bias[hl * 2 + 1];
        r0 = 1.0f / (1.0f + __expf(-r0));
        r1 = 1.0f / (1.0f + __expf(-r1));
        *(float2*)(out + (size_t)v * 64 + hl * 2) = make_float2(r0, r1);
    }
}

// ---- GEMM: act(H[N,128](bf16) @ W[OUT,128]^T(fp32) + b) -> bf16 -----------

__global__ __launch_bounds__(256) void gemm_kernel(const ushort* __restrict__ Hb,
                                                   const float* __restrict__ W,
                                                   const float* __restrict__ bias,
                                                   ushort* __restrict__ outB,
                                                   int N, int OUT, int relu) {
    __shared__ float Hs[16][65];
    __shared__ float Ws[16][65];
    const int t    = threadIdx.x;
    const int row0 = blockIdx.x * 64;
    const int col0 = blockIdx.y * 64;
    const int tx   = t & 15;
    const int ty   = t >> 4;
    const int lr   = t >> 2;
    const int kq   = (t & 3) * 4;

    float acc[4][4] = {};

    for (int k0 = 0; k0 < NFEAT; k0 += 16) {
        float4 hv = make_float4(0.f, 0.f, 0.f, 0.f);
        const int gr = row0 + lr;
        if (gr < N) {
            ushort4 hu = *(const ushort4*)(Hb + (size_t)gr * NFEAT + k0 + kq);
            hv = make_float4(bf2f(hu.x), bf2f(hu.y), bf2f(hu.z), bf2f(hu.w));
        }
        float4 wv = *(const float4*)(W + (size_t)(col0 + lr) * NFEAT + k0 + kq);
        __syncthreads();
        Hs[kq + 0][lr] = hv.x; Hs[kq + 1][lr] = hv.y; Hs[kq + 2][lr] = hv.z; Hs[kq + 3][lr] = hv.w;
        Ws[kq + 0][lr] = wv.x; Ws[kq + 1][lr] = wv.y; Ws[kq + 2][lr] = wv.z; Ws[kq + 3][lr] = wv.w;
        __syncthreads();
#pragma unroll
        for (int kk = 0; kk < 16; ++kk) {
            float4 a = *(const float4*)&Hs[kk][ty * 4];
            float4 b = *(const float4*)&Ws[kk][tx * 4];
            float av[4] = {a.x, a.y, a.z, a.w};
            float bv[4] = {b.x, b.y, b.z, b.w};
#pragma unroll
            for (int i = 0; i < 4; ++i)
#pragma unroll
                for (int j = 0; j < 4; ++j) acc[i][j] += av[i] * bv[j];
        }
    }

    float bv[4] = {0.f, 0.f, 0.f, 0.f};
    if (bias) {
#pragma unroll
        for (int j = 0; j < 4; ++j) bv[j] = bias[col0 + tx * 4 + j];
    }
#pragma unroll
    for (int i = 0; i < 4; ++i) {
        int r = row0 + ty * 4 + i;
        if (r >= N) break;
        float v0 = acc[i][0] + bv[0];
        float v1 = acc[i][1] + bv[1];
        float v2 = acc[i][2] + bv[2];
        float v3 = acc[i][3] + bv[3];
        if (relu) {
            v0 = fmaxf(v0, 0.f); v1 = fmaxf(v1, 0.f);
            v2 = fmaxf(v2, 0.f); v3 = fmaxf(v3, 0.f);
        }
        size_t base = (size_t)r * OUT + col0 + tx * 4;
        *(ushort4*)(outB + base) = make_ushort4(f2bf(v0), f2bf(v1), f2bf(v2), f2bf(v3));
    }
}

// ---------------------------------------------------------------------------

static inline size_t align256(size_t x) { return (x + 255) & ~(size_t)255; }

extern "C" void kernel_launch(void* const* d_in, const int* in_sizes, int n_in,
                              void* d_out, int out_size, void* d_ws, size_t ws_size,
                              hipStream_t stream) {
    const float* x   = (const float*)d_in[0];
    const int*   src = (const int*)d_in[1];
    const int*   dst = (const int*)d_in[2];
    const float* W1  = (const float*)d_in[3];
    const float* b1  = (const float*)d_in[4];
    const float* W2  = (const float*)d_in[5];
    const float* b2  = (const float*)d_in[6];
    const float* W3  = (const float*)d_in[7];
    const float* b3  = (const float*)d_in[8];
    float*       out = (float*)d_out;

    const int N = in_sizes[0] / NFEAT;     // 50000
    const int E = in_sizes[1];             // 800000
    const int D_OUT = in_sizes[7] / NFEAT; // 64
    const int NBUK = (N + (1 << BSH) - 1) >> BSH;   // 391
    const int PBLK = (E + EPB - 1) / EPB;           // 391

    // workspace carve (bf16 feature buffers, aggressive aliasing):
    //   aggB: agg output / GEMM input (N*128 bf16)
    //   xbf : bf16 copy of x       -> reused as h2bf after layer-1 agg
    //   h1bf: gemm1 out            -> reused as gbf after layer-2 agg
    //   pairs (CSR build, 6.4 MB) aliased onto h1bf (dead until gemm1)
    char* ws = (char*)d_ws;
    int* row_ptr      = (int*)ws;  ws += align256((size_t)(N + 1) * 4);
    int* col_idx      = (int*)ws;  ws += align256((size_t)E * 4);
    float* deg_inv    = (float*)ws; ws += align256((size_t)N * 4);
    int* bucketCnt    = (int*)ws;  ws += align256((size_t)NBUKP * 4);
    int* bucketOff    = (int*)ws;  ws += align256((size_t)NBUKP * 4);
    int* bucketCursor = (int*)ws;  ws += align256((size_t)NBUKP * 4);
    ushort* aggB      = (ushort*)ws; ws += align256((size_t)N * NFEAT * 2);
    ushort* xbf       = (ushort*)ws; ws += align256((size_t)N * NFEAT * 2);
    ushort* h1bf      = (ushort*)ws; ws += align256((size_t)N * NFEAT * 2);
    ushort* h2bf = xbf;                       // x dead after layer-1 agg
    ushort* gbf  = h1bf;                      // h1 dead after layer-2 agg
    unsigned long long* pairs = (unsigned long long*)h1bf;  // CSR build only

    // ---- CSR build via 2-level partition ----
    hipMemsetAsync(bucketCnt, 0, (size_t)NBUKP * 4, stream);
    partA1_count<<<PBLK, 256, 0, stream>>>(dst, bucketCnt, E);
    partA2_scan<<<1, NBUKP, 0, stream>>>(bucketCnt, bucketOff, bucketCursor, row_ptr, N, E);
    partA3_scatter<<<PBLK, 256, 0, stream>>>(src, dst, bucketCursor, pairs, E);
    partB_build<<<NBUK, 256, 0, stream>>>(pairs, bucketOff, bucketCnt, row_ptr, deg_inv, col_idx, N);

    const int n4 = N * NFEAT / 4;
    cvt_bf16_kernel<<<(n4 + 255) / 256, 256, 0, stream>>>(x, xbf, n4);

    const int agg128Blocks = (N + 3) / 4;   // 1 node/wave, 4 waves/block
    const int agg64Blocks  = (N + 7) / 8;   // 2 nodes/wave
    dim3 gemmGrid128((N + 63) / 64, NFEAT / 64);
    dim3 gemmGrid64((N + 63) / 64, D_OUT / 64);

    // layer 1
    agg128_kernel<<<agg128Blocks, 256, 0, stream>>>(xbf, row_ptr, col_idx, deg_inv, aggB, N);
    gemm_kernel<<<gemmGrid128, 256, 0, stream>>>(aggB, W1, b1, h1bf, N, NFEAT, 1);
    // layer 2
    agg128_kernel<<<agg128Blocks, 256, 0, stream>>>(h1bf, row_ptr, col_idx, deg_inv, aggB, N);
    gemm_kernel<<<gemmGrid128, 256, 0, stream>>>(aggB, W2, b2, h2bf, N, NFEAT, 1);
    // layer 3 (reordered): g = h2 @ W3^T, then aggregate + bias + sigmoid
    gemm_kernel<<<gemmGrid64, 256, 0, stream>>>(h2bf, W3, nullptr, gbf, N, D_OUT, 0);
    agg64_sigmoid_kernel<<<agg64Blocks, 256, 0, stream>>>(gbf, row_ptr, col_idx, deg_inv, b3, out, N);
}

// Round 6
// 268.494 us; speedup vs baseline: 2.3757x; 1.1735x over previous
//
#include <hip/hip_runtime.h>
#include <hip/hip_bf16.h>
#include <math.h>

// ---------------------------------------------------------------------------
// GraphSAGE (gcn aggregator) x3 layers.
// R6: GEMMs moved to MFMA (mfma_f32_16x16x32_bf16). Both operands bf16
//     (H already bf16 from agg; W converted once/call). No LDS in GEMM ->
//     the 5.6M LDS bank conflicts of the R5 vector GEMM are gone.
//     One wave = 16-row stripe (50000 = 16*3125, no tail), direct global
//     fragment loads, fused bias+relu epilogue, bf16 out.
// ---------------------------------------------------------------------------

#define NFEAT 128
#define BSH   7                 // bucket shift: 128 nodes per bucket
#define NBUKP 512               // padded bucket count (actual 391)
#define EPB   2048              // edges per block in partition passes
#define BCAP  3072              // max edges per bucket handled in LDS

typedef __attribute__((ext_vector_type(8))) short bf16x8;  // 8 bf16 = 4 VGPRs
typedef __attribute__((ext_vector_type(4))) float f32x4;

__device__ __forceinline__ unsigned short f2bf(float f) {  // RTNE fp32->bf16
    unsigned u = __float_as_uint(f);
    u += 0x7fffu + ((u >> 16) & 1u);
    return (unsigned short)(u >> 16);
}
__device__ __forceinline__ float bflo(unsigned u) { return __uint_as_float(u << 16); }
__device__ __forceinline__ float bfhi(unsigned u) { return __uint_as_float(u & 0xffff0000u); }

// ---- Pass A1: coarse bucket histogram -------------------------------------

__global__ __launch_bounds__(256) void partA1_count(const int* __restrict__ dst,
                                                    int* __restrict__ bucketCnt, int E) {
    __shared__ int hist[NBUKP];
    const int t = threadIdx.x;
    hist[t] = 0; hist[t + 256] = 0;
    __syncthreads();
    const int base = blockIdx.x * EPB;
#pragma unroll
    for (int j = 0; j < EPB / 256; ++j) {
        int e = base + t + 256 * j;
        if (e < E) atomicAdd(&hist[dst[e] >> BSH], 1);
    }
    __syncthreads();
    for (int b = t; b < NBUKP; b += 256) {
        int h = hist[b];
        if (h > 0) atomicAdd(&bucketCnt[b], h);
    }
}

// ---- Pass A2: scan bucket counts -> bucketOff, bucketCursor ---------------

__global__ __launch_bounds__(512) void partA2_scan(const int* __restrict__ bucketCnt,
                                                   int* __restrict__ bucketOff,
                                                   int* __restrict__ bucketCursor,
                                                   int* __restrict__ row_ptr, int N, int E) {
    __shared__ int sc[NBUKP];
    const int t = threadIdx.x;
    sc[t] = bucketCnt[t];
    __syncthreads();
    for (int off = 1; off < NBUKP; off <<= 1) {
        int v = (t >= off) ? sc[t - off] : 0;
        __syncthreads();
        sc[t] += v;
        __syncthreads();
    }
    int excl = sc[t] - bucketCnt[t];
    bucketOff[t] = excl;
    bucketCursor[t] = excl;
    if (t == 0) row_ptr[N] = E;
}

// ---- Pass A3: LDS-staged scatter of (src,dst) pairs grouped by bucket -----

__global__ __launch_bounds__(256) void partA3_scatter(const int* __restrict__ src,
                                                      const int* __restrict__ dst,
                                                      int* __restrict__ bucketCursor,
                                                      unsigned long long* __restrict__ pairs,
                                                      int E) {
    __shared__ int hist[NBUKP];
    __shared__ int sc[NBUKP];
    __shared__ int lcur[NBUKP];
    __shared__ int lbase[NBUKP];
    __shared__ unsigned long long stage[EPB];
    __shared__ int destIdx[EPB];
    __shared__ int nLocalSh;

    const int t = threadIdx.x;
    hist[t] = 0; hist[t + 256] = 0;
    lcur[t] = 0; lcur[t + 256] = 0;
    __syncthreads();

    const int base = blockIdx.x * EPB;
    int bb[EPB / 256];
    unsigned long long pr[EPB / 256];
#pragma unroll
    for (int j = 0; j < EPB / 256; ++j) {
        int e = base + t + 256 * j;
        bb[j] = -1;
        if (e < E) {
            int s = src[e], d = dst[e];
            int b = d >> BSH;
            bb[j] = b;
            pr[j] = ((unsigned long long)(unsigned)d << 32) | (unsigned)s;
            atomicAdd(&hist[b], 1);
        }
    }
    __syncthreads();
    sc[t] = hist[t]; sc[t + 256] = hist[t + 256];
    __syncthreads();
    for (int off = 1; off < NBUKP; off <<= 1) {
        int v0 = (t >= off) ? sc[t - off] : 0;
        int v1 = (t + 256 >= off) ? sc[t + 256 - off] : 0;
        __syncthreads();
        sc[t] += v0; sc[t + 256] += v1;
        __syncthreads();
    }
    if (t == 255) nLocalSh = sc[NBUKP - 1];
    sc[t] -= hist[t]; sc[t + 256] -= hist[t + 256];
    for (int b = t; b < NBUKP; b += 256) {
        int h = hist[b];
        if (h > 0) lbase[b] = atomicAdd(&bucketCursor[b], h);
    }
    __syncthreads();
#pragma unroll
    for (int j = 0; j < EPB / 256; ++j) {
        int b = bb[j];
        if (b >= 0) {
            int slot = atomicAdd(&lcur[b], 1);
            int spos = sc[b] + slot;
            stage[spos] = pr[j];
            destIdx[spos] = lbase[b] + slot;
        }
    }
    __syncthreads();
    const int nLocal = nLocalSh;
#pragma unroll
    for (int j = 0; j < EPB / 256; ++j) {
        int i = t + 256 * j;
        if (i < nLocal) pairs[destIdx[i]] = stage[i];
    }
}

// ---- Pass B: per-bucket sort by dst, emit row_ptr/deg_inv/col_idx ---------

__global__ __launch_bounds__(256) void partB_build(const unsigned long long* __restrict__ pairs,
                                                   const int* __restrict__ bucketOff,
                                                   const int* __restrict__ bucketCnt,
                                                   int* __restrict__ row_ptr,
                                                   float* __restrict__ deg_inv,
                                                   int* __restrict__ col_idx, int N) {
    __shared__ unsigned long long pairsL[BCAP];
    __shared__ int srcS[BCAP];
    __shared__ int nhist[128];
    __shared__ int npref[128];
    __shared__ int ncur[128];

    const int t = threadIdx.x;
    const int b = blockIdx.x;
    const int nodeBase = b << BSH;
    const int eBeg = bucketOff[b];
    const int eCnt = bucketCnt[b];

    if (t < 128) { nhist[t] = 0; ncur[t] = 0; }
    __syncthreads();

    if (eCnt <= BCAP) {
        for (int i = t; i < eCnt; i += 256) {
            unsigned long long p = pairs[eBeg + i];
            pairsL[i] = p;
            atomicAdd(&nhist[(int)(p >> 32) - nodeBase], 1);
        }
        __syncthreads();
        if (t < 128) npref[t] = nhist[t];
        __syncthreads();
        for (int off = 1; off < 128; off <<= 1) {
            int v = (t < 128 && t >= off) ? npref[t - off] : 0;
            __syncthreads();
            if (t < 128) npref[t] += v;
            __syncthreads();
        }
        if (t < 128) npref[t] -= nhist[t];
        if (t < 128 && nodeBase + t < N) {
            row_ptr[nodeBase + t] = eBeg + npref[t];
            deg_inv[nodeBase + t] = 1.0f / (float)(nhist[t] + 1);
        }
        __syncthreads();
        for (int i = t; i < eCnt; i += 256) {
            unsigned long long p = pairsL[i];
            int d = (int)(p >> 32) - nodeBase;
            int slot = atomicAdd(&ncur[d], 1);
            srcS[npref[d] + slot] = (int)(unsigned)p;
        }
        __syncthreads();
        for (int i = t; i < eCnt; i += 256) col_idx[eBeg + i] = srcS[i];
    } else {
        for (int i = t; i < eCnt; i += 256) {
            unsigned long long p = pairs[eBeg + i];
            atomicAdd(&nhist[(int)(p >> 32) - nodeBase], 1);
        }
        __syncthreads();
        if (t < 128) npref[t] = nhist[t];
        __syncthreads();
        for (int off = 1; off < 128; off <<= 1) {
            int v = (t < 128 && t >= off) ? npref[t - off] : 0;
            __syncthreads();
            if (t < 128) npref[t] += v;
            __syncthreads();
        }
        if (t < 128) npref[t] -= nhist[t];
        if (t < 128 && nodeBase + t < N) {
            row_ptr[nodeBase + t] = eBeg + npref[t];
            deg_inv[nodeBase + t] = 1.0f / (float)(nhist[t] + 1);
        }
        __syncthreads();
        for (int i = t; i < eCnt; i += 256) {
            unsigned long long p = pairs[eBeg + i];
            int d = (int)(p >> 32) - nodeBase;
            int slot = atomicAdd(&ncur[d], 1);
            col_idx[eBeg + npref[d] + slot] = (int)(unsigned)p;
        }
    }
}

// ---- fp32 -> bf16 convert -------------------------------------------------

__global__ __launch_bounds__(256) void cvt_bf16_kernel(const float* __restrict__ in,
                                                       ushort* __restrict__ outb, int n4) {
    int i = blockIdx.x * blockDim.x + threadIdx.x;
    if (i < n4) {
        float4 f = *(const float4*)(in + (size_t)i * 4);
        ushort4 u = make_ushort4(f2bf(f.x), f2bf(f.y), f2bf(f.z), f2bf(f.w));
        *(ushort4*)(outb + (size_t)i * 4) = u;
    }
}

// ---- Aggregation (128 feats, bf16 in/out): 1 node/wave, reg-cidx, MLP=4 ---

__global__ __launch_bounds__(256) void agg128_kernel(const ushort* __restrict__ Xb,
                                                     const int* __restrict__ row_ptr,
                                                     const int* __restrict__ col_idx,
                                                     const float* __restrict__ deg_inv,
                                                     ushort* __restrict__ Hb, int N) {
    const int v    = blockIdx.x * (blockDim.x >> 6) + (threadIdx.x >> 6);
    const int lane = threadIdx.x & 63;
    if (v >= N) return;
    const int beg = row_ptr[v];
    const int end = row_ptr[v + 1];
    const int deg = end - beg;
    const unsigned* Xu = (const unsigned*)Xb;  // row stride 64 uints

    int cidx = 0;
    if (lane < deg) cidx = col_idx[beg + lane];

    float a0 = 0.f, a1 = 0.f, b0 = 0.f, b1 = 0.f;
    float c0 = 0.f, c1 = 0.f, d0 = 0.f, d1 = 0.f;
    const int nfast = deg < 64 ? deg : 64;
    int j = 0;
    for (; j + 3 < nfast; j += 4) {
        int s0 = __shfl(cidx, j + 0, 64);
        int s1 = __shfl(cidx, j + 1, 64);
        int s2 = __shfl(cidx, j + 2, 64);
        int s3 = __shfl(cidx, j + 3, 64);
        unsigned u0 = Xu[(size_t)s0 * 64 + lane];
        unsigned u1 = Xu[(size_t)s1 * 64 + lane];
        unsigned u2 = Xu[(size_t)s2 * 64 + lane];
        unsigned u3 = Xu[(size_t)s3 * 64 + lane];
        a0 += bflo(u0); a1 += bfhi(u0);
        b0 += bflo(u1); b1 += bfhi(u1);
        c0 += bflo(u2); c1 += bfhi(u2);
        d0 += bflo(u3); d1 += bfhi(u3);
    }
    for (; j < nfast; ++j) {
        int s0 = __shfl(cidx, j, 64);
        unsigned u0 = Xu[(size_t)s0 * 64 + lane];
        a0 += bflo(u0); a1 += bfhi(u0);
    }
    for (int e = beg + 64; e < end; ++e) {   // rare: deg > 64
        unsigned u0 = Xu[(size_t)col_idx[e] * 64 + lane];
        a0 += bflo(u0); a1 += bfhi(u0);
    }
    unsigned us = Xu[(size_t)v * 64 + lane];
    float inv = deg_inv[v];
    float r0 = (a0 + b0 + c0 + d0 + bflo(us)) * inv;
    float r1 = (a1 + b1 + c1 + d1 + bfhi(us)) * inv;
    unsigned ru = (unsigned)f2bf(r0) | ((unsigned)f2bf(r1) << 16);
    ((unsigned*)Hb)[(size_t)v * 64 + lane] = ru;
}

// ---- Final aggregation (64 feats, bf16) + bias + sigmoid ------------------

__global__ __launch_bounds__(256) void agg64_sigmoid_kernel(const ushort* __restrict__ Gb,
                                                            const int* __restrict__ row_ptr,
                                                            const int* __restrict__ col_idx,
                                                            const float* __restrict__ deg_inv,
                                                            const float* __restrict__ bias,
                                                            float* __restrict__ out, int N) {
    const int wp   = blockIdx.x * (blockDim.x >> 6) + (threadIdx.x >> 6);
    const int lane = threadIdx.x & 63;
    const int half = lane >> 5;
    const int hl   = lane & 31;
    const int v    = wp * 2 + half;
    const bool act = (v < N);

    int beg = 0, end = 0;
    if (act) { beg = row_ptr[v]; end = row_ptr[v + 1]; }
    const int deg = end - beg;
    const unsigned* Gu = (const unsigned*)Gb;  // row stride 32 uints

    int cidx = 0;
    if (hl < deg) cidx = col_idx[beg + hl];

    float a0 = 0.f, a1 = 0.f, b0 = 0.f, b1 = 0.f;
    float c0 = 0.f, c1 = 0.f, d0 = 0.f, d1 = 0.f;
    const int nfast = deg < 32 ? deg : 32;
    int j = 0;
    for (; j + 3 < nfast; j += 4) {
        int s0 = __shfl(cidx, j + 0, 32);
        int s1 = __shfl(cidx, j + 1, 32);
        int s2 = __shfl(cidx, j + 2, 32);
        int s3 = __shfl(cidx, j + 3, 32);
        unsigned u0 = Gu[(size_t)s0 * 32 + hl];
        unsigned u1 = Gu[(size_t)s1 * 32 + hl];
        unsigned u2 = Gu[(size_t)s2 * 32 + hl];
        unsigned u3 = Gu[(size_t)s3 * 32 + hl];
        a0 += bflo(u0); a1 += bfhi(u0);
        b0 += bflo(u1); b1 += bfhi(u1);
        c0 += bflo(u2); c1 += bfhi(u2);
        d0 += bflo(u3); d1 += bfhi(u3);
    }
    for (; j < nfast; ++j) {
        int s0 = __shfl(cidx, j, 32);
        unsigned u0 = Gu[(size_t)s0 * 32 + hl];
        a0 += bflo(u0); a1 += bfhi(u0);
    }
    for (int e = beg + 32; e < end; ++e) {
        unsigned u0 = Gu[(size_t)col_idx[e] * 32 + hl];
        a0 += bflo(u0); a1 += bfhi(u0);
    }
    if (act) {
        unsigned us = Gu[(size_t)v * 32 + hl];
        float inv = deg_inv[v];
        float r0 = (a0 + b0 + c0 + d0 + bflo(us)) * inv + bias[hl * 2 + 0];
        float r1 = (a1 + b1 + c1 + d1 + bfhi(us)) * inv + bias[hl * 2 + 1];
        r0 = 1.0f / (1.0f + __expf(-r0));
        r1 = 1.0f / (1.0f + __expf(-r1));
        *(float2*)(out + (size_t)v * 64 + hl * 2) = make_float2(r0, r1);
    }
}

// ---- MFMA GEMM: out[N,OUT](bf16) = act(H[N,128](bf16) @ W[OUT,128]^T(bf16) + b)
// One wave = 16-row stripe. A frag: H[row0+m][k0 + quad*8 + j] (16B/lane).
// B frag: W[ct*16 + n][k0 + quad*8 + j], n = lane&15. No LDS.
// C/D layout (verified m89/m91): col = lane&15, row = quad*4 + reg.

template<int NCT>
__global__ __launch_bounds__(256) void gemm_mfma_kernel(const ushort* __restrict__ Hb,
                                                        const ushort* __restrict__ Wb,
                                                        const float* __restrict__ bias,
                                                        ushort* __restrict__ outB,
                                                        int N, int relu) {
    const int OUT  = NCT * 16;
    const int wid  = blockIdx.x * 4 + (threadIdx.x >> 6);
    const int lane = threadIdx.x & 63;
    const int m    = lane & 15;
    const int quad = lane >> 4;
    const int row0 = wid * 16;
    if (row0 >= N) return;

    f32x4 acc[NCT];
#pragma unroll
    for (int i = 0; i < NCT; ++i) acc[i] = (f32x4){0.f, 0.f, 0.f, 0.f};

    const ushort* hrow = Hb + (size_t)(row0 + m) * NFEAT + quad * 8;
    const ushort* wrow = Wb + (size_t)m * NFEAT + quad * 8;

#pragma unroll
    for (int k0 = 0; k0 < NFEAT; k0 += 32) {
        bf16x8 a = *(const bf16x8*)(hrow + k0);
#pragma unroll
        for (int ct = 0; ct < NCT; ++ct) {
            bf16x8 b = *(const bf16x8*)(wrow + (size_t)ct * 16 * NFEAT + k0);
            acc[ct] = __builtin_amdgcn_mfma_f32_16x16x32_bf16(a, b, acc[ct], 0, 0, 0);
        }
    }

#pragma unroll
    for (int ct = 0; ct < NCT; ++ct) {
        float bv = bias ? bias[ct * 16 + m] : 0.f;
#pragma unroll
        for (int r = 0; r < 4; ++r) {
            float v = acc[ct][r] + bv;
            if (relu) v = fmaxf(v, 0.f);
            int row = row0 + quad * 4 + r;
            outB[(size_t)row * OUT + ct * 16 + m] = f2bf(v);
        }
    }
}

// ---------------------------------------------------------------------------

static inline size_t align256(size_t x) { return (x + 255) & ~(size_t)255; }

extern "C" void kernel_launch(void* const* d_in, const int* in_sizes, int n_in,
                              void* d_out, int out_size, void* d_ws, size_t ws_size,
                              hipStream_t stream) {
    const float* x   = (const float*)d_in[0];
    const int*   src = (const int*)d_in[1];
    const int*   dst = (const int*)d_in[2];
    const float* W1  = (const float*)d_in[3];
    const float* b1  = (const float*)d_in[4];
    const float* W2  = (const float*)d_in[5];
    const float* b2  = (const float*)d_in[6];
    const float* W3  = (const float*)d_in[7];
    const float* b3  = (const float*)d_in[8];
    float*       out = (float*)d_out;

    const int N = in_sizes[0] / NFEAT;     // 50000
    const int E = in_sizes[1];             // 800000
    const int D_OUT = in_sizes[7] / NFEAT; // 64
    const int NBUK = (N + (1 << BSH) - 1) >> BSH;   // 391
    const int PBLK = (E + EPB - 1) / EPB;           // 391

    // workspace carve (bf16 feature buffers, aggressive aliasing):
    char* ws = (char*)d_ws;
    int* row_ptr      = (int*)ws;  ws += align256((size_t)(N + 1) * 4);
    int* col_idx      = (int*)ws;  ws += align256((size_t)E * 4);
    float* deg_inv    = (float*)ws; ws += align256((size_t)N * 4);
    int* bucketCnt    = (int*)ws;  ws += align256((size_t)NBUKP * 4);
    int* bucketOff    = (int*)ws;  ws += align256((size_t)NBUKP * 4);
    int* bucketCursor = (int*)ws;  ws += align256((size_t)NBUKP * 4);
    ushort* w1bf      = (ushort*)ws; ws += align256((size_t)NFEAT * NFEAT * 2);
    ushort* w2bf      = (ushort*)ws; ws += align256((size_t)NFEAT * NFEAT * 2);
    ushort* w3bf      = (ushort*)ws; ws += align256((size_t)D_OUT * NFEAT * 2);
    ushort* aggB      = (ushort*)ws; ws += align256((size_t)N * NFEAT * 2);
    ushort* xbf       = (ushort*)ws; ws += align256((size_t)N * NFEAT * 2);
    ushort* h1bf      = (ushort*)ws; ws += align256((size_t)N * NFEAT * 2);
    ushort* h2bf = xbf;                       // x dead after layer-1 agg
    ushort* gbf  = h1bf;                      // h1 dead after layer-2 agg
    unsigned long long* pairs = (unsigned long long*)h1bf;  // CSR build only

    // ---- CSR build via 2-level partition ----
    hipMemsetAsync(bucketCnt, 0, (size_t)NBUKP * 4, stream);
    partA1_count<<<PBLK, 256, 0, stream>>>(dst, bucketCnt, E);
    partA2_scan<<<1, NBUKP, 0, stream>>>(bucketCnt, bucketOff, bucketCursor, row_ptr, N, E);
    partA3_scatter<<<PBLK, 256, 0, stream>>>(src, dst, bucketCursor, pairs, E);
    partB_build<<<NBUK, 256, 0, stream>>>(pairs, bucketOff, bucketCnt, row_ptr, deg_inv, col_idx, N);

    // ---- convert x and weights to bf16 ----
    const int n4 = N * NFEAT / 4;
    cvt_bf16_kernel<<<(n4 + 255) / 256, 256, 0, stream>>>(x, xbf, n4);
    cvt_bf16_kernel<<<(NFEAT * NFEAT / 4 + 255) / 256, 256, 0, stream>>>(W1, w1bf, NFEAT * NFEAT / 4);
    cvt_bf16_kernel<<<(NFEAT * NFEAT / 4 + 255) / 256, 256, 0, stream>>>(W2, w2bf, NFEAT * NFEAT / 4);
    cvt_bf16_kernel<<<(D_OUT * NFEAT / 4 + 255) / 256, 256, 0, stream>>>(W3, w3bf, D_OUT * NFEAT / 4);

    const int agg128Blocks = (N + 3) / 4;   // 1 node/wave
    const int agg64Blocks  = (N + 7) / 8;   // 2 nodes/wave
    const int gemmBlocks   = (N / 16 + 3) / 4;  // 1 wave per 16-row stripe

    // layer 1
    agg128_kernel<<<agg128Blocks, 256, 0, stream>>>(xbf, row_ptr, col_idx, deg_inv, aggB, N);
    gemm_mfma_kernel<8><<<gemmBlocks, 256, 0, stream>>>(aggB, w1bf, b1, h1bf, N, 1);
    // layer 2
    agg128_kernel<<<agg128Blocks, 256, 0, stream>>>(h1bf, row_ptr, col_idx, deg_inv, aggB, N);
    gemm_mfma_kernel<8><<<gemmBlocks, 256, 0, stream>>>(aggB, w2bf, b2, h2bf, N, 1);
    // layer 3 (reordered): g = h2 @ W3^T, then aggregate + bias + sigmoid
    gemm_mfma_kernel<4><<<gemmBlocks, 256, 0, stream>>>(h2bf, w3bf, nullptr, gbf, N, 0);
    agg64_sigmoid_kernel<<<agg64Blocks, 256, 0, stream>>>(gbf, row_ptr, col_idx, deg_inv, b3, out, N);
}

// Round 7
// 241.582 us; speedup vs baseline: 2.6404x; 1.1114x over previous
//
#include <hip/hip_runtime.h>
#include <hip/hip_bf16.h>
#include <math.h>

// ---------------------------------------------------------------------------
// GraphSAGE (gcn aggregator) x3 layers.
// R7: fused per-16-node-block pipeline:
//   fused<0>: agg(xbf) -> LDS tile -> MFMA W1 + bias + relu -> h1bf
//   fused<1>: agg(h1bf) -> LDS -> MFMA W2+b2+relu -> LDS -> MFMA W3 -> gbf
//   agg64_sigmoid: gather gbf + bias + sigmoid -> out
// Removes aggB and h2bf round trips (~64 MB streaming) and 4 launches.
// LDS tiles padded to 136 shorts/row -> MFMA A-frag ds_read_b128 is a free
// 2-way bank conflict.
// ---------------------------------------------------------------------------

#define NFEAT 128
#define BSH   7                 // bucket shift: 128 nodes per bucket
#define NBUKP 512               // padded bucket count (actual 391)
#define EPB   2048              // edges per block in partition passes
#define BCAP  3072              // max edges per bucket handled in LDS

typedef __attribute__((ext_vector_type(8))) short bf16x8;  // 8 bf16 = 4 VGPRs
typedef __attribute__((ext_vector_type(4))) float f32x4;

__device__ __forceinline__ unsigned short f2bf(float f) {  // RTNE fp32->bf16
    unsigned u = __float_as_uint(f);
    u += 0x7fffu + ((u >> 16) & 1u);
    return (unsigned short)(u >> 16);
}
__device__ __forceinline__ float bflo(unsigned u) { return __uint_as_float(u << 16); }
__device__ __forceinline__ float bfhi(unsigned u) { return __uint_as_float(u & 0xffff0000u); }

// ---- Pass A1: coarse bucket histogram -------------------------------------

__global__ __launch_bounds__(256) void partA1_count(const int* __restrict__ dst,
                                                    int* __restrict__ bucketCnt, int E) {
    __shared__ int hist[NBUKP];
    const int t = threadIdx.x;
    hist[t] = 0; hist[t + 256] = 0;
    __syncthreads();
    const int base = blockIdx.x * EPB;
#pragma unroll
    for (int j = 0; j < EPB / 256; ++j) {
        int e = base + t + 256 * j;
        if (e < E) atomicAdd(&hist[dst[e] >> BSH], 1);
    }
    __syncthreads();
    for (int b = t; b < NBUKP; b += 256) {
        int h = hist[b];
        if (h > 0) atomicAdd(&bucketCnt[b], h);
    }
}

// ---- Pass A2: scan bucket counts -> bucketOff, bucketCursor ---------------

__global__ __launch_bounds__(512) void partA2_scan(const int* __restrict__ bucketCnt,
                                                   int* __restrict__ bucketOff,
                                                   int* __restrict__ bucketCursor,
                                                   int* __restrict__ row_ptr, int N, int E) {
    __shared__ int sc[NBUKP];
    const int t = threadIdx.x;
    sc[t] = bucketCnt[t];
    __syncthreads();
    for (int off = 1; off < NBUKP; off <<= 1) {
        int v = (t >= off) ? sc[t - off] : 0;
        __syncthreads();
        sc[t] += v;
        __syncthreads();
    }
    int excl = sc[t] - bucketCnt[t];
    bucketOff[t] = excl;
    bucketCursor[t] = excl;
    if (t == 0) row_ptr[N] = E;
}

// ---- Pass A3: LDS-staged scatter of (src,dst) pairs grouped by bucket -----

__global__ __launch_bounds__(256) void partA3_scatter(const int* __restrict__ src,
                                                      const int* __restrict__ dst,
                                                      int* __restrict__ bucketCursor,
                                                      unsigned long long* __restrict__ pairs,
                                                      int E) {
    __shared__ int hist[NBUKP];
    __shared__ int sc[NBUKP];
    __shared__ int lcur[NBUKP];
    __shared__ int lbase[NBUKP];
    __shared__ unsigned long long stage[EPB];
    __shared__ int destIdx[EPB];
    __shared__ int nLocalSh;

    const int t = threadIdx.x;
    hist[t] = 0; hist[t + 256] = 0;
    lcur[t] = 0; lcur[t + 256] = 0;
    __syncthreads();

    const int base = blockIdx.x * EPB;
    int bb[EPB / 256];
    unsigned long long pr[EPB / 256];
#pragma unroll
    for (int j = 0; j < EPB / 256; ++j) {
        int e = base + t + 256 * j;
        bb[j] = -1;
        if (e < E) {
            int s = src[e], d = dst[e];
            int b = d >> BSH;
            bb[j] = b;
            pr[j] = ((unsigned long long)(unsigned)d << 32) | (unsigned)s;
            atomicAdd(&hist[b], 1);
        }
    }
    __syncthreads();
    sc[t] = hist[t]; sc[t + 256] = hist[t + 256];
    __syncthreads();
    for (int off = 1; off < NBUKP; off <<= 1) {
        int v0 = (t >= off) ? sc[t - off] : 0;
        int v1 = (t + 256 >= off) ? sc[t + 256 - off] : 0;
        __syncthreads();
        sc[t] += v0; sc[t + 256] += v1;
        __syncthreads();
    }
    if (t == 255) nLocalSh = sc[NBUKP - 1];
    sc[t] -= hist[t]; sc[t + 256] -= hist[t + 256];
    for (int b = t; b < NBUKP; b += 256) {
        int h = hist[b];
        if (h > 0) lbase[b] = atomicAdd(&bucketCursor[b], h);
    }
    __syncthreads();
#pragma unroll
    for (int j = 0; j < EPB / 256; ++j) {
        int b = bb[j];
        if (b >= 0) {
            int slot = atomicAdd(&lcur[b], 1);
            int spos = sc[b] + slot;
            stage[spos] = pr[j];
            destIdx[spos] = lbase[b] + slot;
        }
    }
    __syncthreads();
    const int nLocal = nLocalSh;
#pragma unroll
    for (int j = 0; j < EPB / 256; ++j) {
        int i = t + 256 * j;
        if (i < nLocal) pairs[destIdx[i]] = stage[i];
    }
}

// ---- Pass B: per-bucket sort by dst, emit row_ptr/deg_inv/col_idx ---------

__global__ __launch_bounds__(256) void partB_build(const unsigned long long* __restrict__ pairs,
                                                   const int* __restrict__ bucketOff,
                                                   const int* __restrict__ bucketCnt,
                                                   int* __restrict__ row_ptr,
                                                   float* __restrict__ deg_inv,
                                                   int* __restrict__ col_idx, int N) {
    __shared__ unsigned long long pairsL[BCAP];
    __shared__ int srcS[BCAP];
    __shared__ int nhist[128];
    __shared__ int npref[128];
    __shared__ int ncur[128];

    const int t = threadIdx.x;
    const int b = blockIdx.x;
    const int nodeBase = b << BSH;
    const int eBeg = bucketOff[b];
    const int eCnt = bucketCnt[b];

    if (t < 128) { nhist[t] = 0; ncur[t] = 0; }
    __syncthreads();

    if (eCnt <= BCAP) {
        for (int i = t; i < eCnt; i += 256) {
            unsigned long long p = pairs[eBeg + i];
            pairsL[i] = p;
            atomicAdd(&nhist[(int)(p >> 32) - nodeBase], 1);
        }
        __syncthreads();
        if (t < 128) npref[t] = nhist[t];
        __syncthreads();
        for (int off = 1; off < 128; off <<= 1) {
            int v = (t < 128 && t >= off) ? npref[t - off] : 0;
            __syncthreads();
            if (t < 128) npref[t] += v;
            __syncthreads();
        }
        if (t < 128) npref[t] -= nhist[t];
        if (t < 128 && nodeBase + t < N) {
            row_ptr[nodeBase + t] = eBeg + npref[t];
            deg_inv[nodeBase + t] = 1.0f / (float)(nhist[t] + 1);
        }
        __syncthreads();
        for (int i = t; i < eCnt; i += 256) {
            unsigned long long p = pairsL[i];
            int d = (int)(p >> 32) - nodeBase;
            int slot = atomicAdd(&ncur[d], 1);
            srcS[npref[d] + slot] = (int)(unsigned)p;
        }
        __syncthreads();
        for (int i = t; i < eCnt; i += 256) col_idx[eBeg + i] = srcS[i];
    } else {
        for (int i = t; i < eCnt; i += 256) {
            unsigned long long p = pairs[eBeg + i];
            atomicAdd(&nhist[(int)(p >> 32) - nodeBase], 1);
        }
        __syncthreads();
        if (t < 128) npref[t] = nhist[t];
        __syncthreads();
        for (int off = 1; off < 128; off <<= 1) {
            int v = (t < 128 && t >= off) ? npref[t - off] : 0;
            __syncthreads();
            if (t < 128) npref[t] += v;
            __syncthreads();
        }
        if (t < 128) npref[t] -= nhist[t];
        if (t < 128 && nodeBase + t < N) {
            row_ptr[nodeBase + t] = eBeg + npref[t];
            deg_inv[nodeBase + t] = 1.0f / (float)(nhist[t] + 1);
        }
        __syncthreads();
        for (int i = t; i < eCnt; i += 256) {
            unsigned long long p = pairs[eBeg + i];
            int d = (int)(p >> 32) - nodeBase;
            int slot = atomicAdd(&ncur[d], 1);
            col_idx[eBeg + npref[d] + slot] = (int)(unsigned)p;
        }
    }
}

// ---- fp32 -> bf16 converts ------------------------------------------------

__global__ __launch_bounds__(256) void cvt_bf16_kernel(const float* __restrict__ in,
                                                       ushort* __restrict__ outb, int n4) {
    int i = blockIdx.x * blockDim.x + threadIdx.x;
    if (i < n4) {
        float4 f = *(const float4*)(in + (size_t)i * 4);
        ushort4 u = make_ushort4(f2bf(f.x), f2bf(f.y), f2bf(f.z), f2bf(f.w));
        *(ushort4*)(outb + (size_t)i * 4) = u;
    }
}

__global__ __launch_bounds__(256) void cvt_weights_kernel(const float* __restrict__ W1,
                                                          const float* __restrict__ W2,
                                                          const float* __restrict__ W3,
                                                          ushort* __restrict__ w1,
                                                          ushort* __restrict__ w2,
                                                          ushort* __restrict__ w3,
                                                          int n1, int n2, int n3) {
    int i = blockIdx.x * blockDim.x + threadIdx.x;
    const float* src; ushort* dst; int off;
    if (i < n1)            { src = W1; dst = w1; off = i; }
    else if (i < n1 + n2)  { src = W2; dst = w2; off = i - n1; }
    else if (i < n1+n2+n3) { src = W3; dst = w3; off = i - n1 - n2; }
    else return;
    float4 f = *(const float4*)(src + (size_t)off * 4);
    *(ushort4*)(dst + (size_t)off * 4) = make_ushort4(f2bf(f.x), f2bf(f.y), f2bf(f.z), f2bf(f.w));
}

// ---- Fused: 16-node agg -> LDS -> MFMA GEMM(s) ----------------------------
// Block = 256 thr (4 waves), handles nodes [base, base+16).
// Phase 1: wave w aggregates nodes base+4w..base+4w+3 (R5 scheme: col_idx
//          preloaded, __shfl broadcast, 4 gathers in flight) -> LDS A tile.
// Phase 2: C = relu(A @ W^T + b); wave w owns cols [32w, 32w+32).
// Phase 3 (SECOND): G = H2 @ W3^T (64 cols; wave w owns [16w,16w+16)).
// C/D layout (verified m89/m91): col = lane&15, row = quad*4 + reg.

template<int SECOND>
__global__ __launch_bounds__(256) void fused_agg_gemm_kernel(
        const ushort* __restrict__ Xb,
        const int* __restrict__ row_ptr,
        const int* __restrict__ col_idx,
        const float* __restrict__ deg_inv,
        const ushort* __restrict__ Wb,     // [128,128] bf16
        const float* __restrict__ bias,    // [128]
        const ushort* __restrict__ W3b,    // [64,128] bf16 (SECOND only)
        ushort* __restrict__ outB, int N) {
    __shared__ ushort A[16][136];                    // +8 pad: 2-way-free banks
    __shared__ ushort H2[SECOND ? 16 : 1][136];

    const int t    = threadIdx.x;
    const int w    = t >> 6;
    const int lane = t & 63;
    const int base = blockIdx.x * 16;
    const unsigned* Xu = (const unsigned*)Xb;        // row stride 64 uints

    // ---- phase 1: aggregate 4 nodes per wave into LDS ----
#pragma unroll
    for (int i = 0; i < 4; ++i) {
        const int v = base + w * 4 + i;
        if (v < N) {
            const int beg = row_ptr[v];
            const int end = row_ptr[v + 1];
            const int deg = end - beg;
            int cidx = 0;
            if (lane < deg) cidx = col_idx[beg + lane];

            float a0 = 0.f, a1 = 0.f, b0 = 0.f, b1 = 0.f;
            float c0 = 0.f, c1 = 0.f, d0 = 0.f, d1 = 0.f;
            const int nfast = deg < 64 ? deg : 64;
            int j = 0;
            for (; j + 3 < nfast; j += 4) {
                int s0 = __shfl(cidx, j + 0, 64);
                int s1 = __shfl(cidx, j + 1, 64);
                int s2 = __shfl(cidx, j + 2, 64);
                int s3 = __shfl(cidx, j + 3, 64);
                unsigned u0 = Xu[(size_t)s0 * 64 + lane];
                unsigned u1 = Xu[(size_t)s1 * 64 + lane];
                unsigned u2 = Xu[(size_t)s2 * 64 + lane];
                unsigned u3 = Xu[(size_t)s3 * 64 + lane];
                a0 += bflo(u0); a1 += bfhi(u0);
                b0 += bflo(u1); b1 += bfhi(u1);
                c0 += bflo(u2); c1 += bfhi(u2);
                d0 += bflo(u3); d1 += bfhi(u3);
            }
            for (; j < nfast; ++j) {
                int s0 = __shfl(cidx, j, 64);
                unsigned u0 = Xu[(size_t)s0 * 64 + lane];
                a0 += bflo(u0); a1 += bfhi(u0);
            }
            for (int e = beg + 64; e < end; ++e) {   // rare: deg > 64
                unsigned u0 = Xu[(size_t)col_idx[e] * 64 + lane];
                a0 += bflo(u0); a1 += bfhi(u0);
            }
            unsigned us = Xu[(size_t)v * 64 + lane];
            float inv = deg_inv[v];
            float r0 = (a0 + b0 + c0 + d0 + bflo(us)) * inv;
            float r1 = (a1 + b1 + c1 + d1 + bfhi(us)) * inv;
            unsigned ru = (unsigned)f2bf(r0) | ((unsigned)f2bf(r1) << 16);
            ((unsigned*)&A[w * 4 + i][0])[lane] = ru;
        }
    }
    __syncthreads();

    // ---- phase 2: relu(A @ W^T + b), wave w -> cols [32w, 32w+32) ----
    const int m    = lane & 15;
    const int quad = lane >> 4;
    f32x4 acc0 = {0.f, 0.f, 0.f, 0.f};
    f32x4 acc1 = {0.f, 0.f, 0.f, 0.f};
    {
        const ushort* arow = &A[m][quad * 8];
        const ushort* wrow = Wb + (size_t)(w * 32 + m) * NFEAT + quad * 8;
#pragma unroll
        for (int k0 = 0; k0 < NFEAT; k0 += 32) {
            bf16x8 a  = *(const bf16x8*)(arow + k0);
            bf16x8 bA = *(const bf16x8*)(wrow + k0);
            bf16x8 bB = *(const bf16x8*)(wrow + 16 * NFEAT + k0);
            acc0 = __builtin_amdgcn_mfma_f32_16x16x32_bf16(a, bA, acc0, 0, 0, 0);
            acc1 = __builtin_amdgcn_mfma_f32_16x16x32_bf16(a, bB, acc1, 0, 0, 0);
        }
    }
    const float bv0 = bias[w * 32 + m];
    const float bv1 = bias[w * 32 + 16 + m];

    if (!SECOND) {
#pragma unroll
        for (int r = 0; r < 4; ++r) {
            int row = base + quad * 4 + r;
            if (row < N) {
                outB[(size_t)row * NFEAT + w * 32 + m]      = f2bf(fmaxf(acc0[r] + bv0, 0.f));
                outB[(size_t)row * NFEAT + w * 32 + 16 + m] = f2bf(fmaxf(acc1[r] + bv1, 0.f));
            }
        }
    } else {
#pragma unroll
        for (int r = 0; r < 4; ++r) {
            H2[quad * 4 + r][w * 32 + m]      = f2bf(fmaxf(acc0[r] + bv0, 0.f));
            H2[quad * 4 + r][w * 32 + 16 + m] = f2bf(fmaxf(acc1[r] + bv1, 0.f));
        }
        __syncthreads();
        // ---- phase 3: G = H2 @ W3^T, wave w -> cols [16w, 16w+16) ----
        f32x4 acc3 = {0.f, 0.f, 0.f, 0.f};
        const ushort* hrow  = &H2[m][quad * 8];
        const ushort* w3row = W3b + (size_t)(w * 16 + m) * NFEAT + quad * 8;
#pragma unroll
        for (int k0 = 0; k0 < NFEAT; k0 += 32) {
            bf16x8 a = *(const bf16x8*)(hrow + k0);
            bf16x8 b = *(const bf16x8*)(w3row + k0);
            acc3 = __builtin_amdgcn_mfma_f32_16x16x32_bf16(a, b, acc3, 0, 0, 0);
        }
#pragma unroll
        for (int r = 0; r < 4; ++r) {
            int row = base + quad * 4 + r;
            if (row < N) outB[(size_t)row * 64 + w * 16 + m] = f2bf(acc3[r]);
        }
    }
}

// ---- Final aggregation (64 feats, bf16) + bias + sigmoid ------------------

__global__ __launch_bounds__(256) void agg64_sigmoid_kernel(const ushort* __restrict__ Gb,
                                                            const int* __restrict__ row_ptr,
                                                            const int* __restrict__ col_idx,
                                                            const float* __restrict__ deg_inv,
                                                            const float* __restrict__ bias,
                                                            float* __restrict__ out, int N) {
    const int wp   = blockIdx.x * (blockDim.x >> 6) + (threadIdx.x >> 6);
    const int lane = threadIdx.x & 63;
    const int half = lane >> 5;
    const int hl   = lane & 31;
    const int v    = wp * 2 + half;
    const bool act = (v < N);

    int beg = 0, end = 0;
    if (act) { beg = row_ptr[v]; end = row_ptr[v + 1]; }
    const int deg = end - beg;
    const unsigned* Gu = (const unsigned*)Gb;  // row stride 32 uints

    int cidx = 0;
    if (hl < deg) cidx = col_idx[beg + hl];

    float a0 = 0.f, a1 = 0.f, b0 = 0.f, b1 = 0.f;
    float c0 = 0.f, c1 = 0.f, d0 = 0.f, d1 = 0.f;
    const int nfast = deg < 32 ? deg : 32;
    int j = 0;
    for (; j + 3 < nfast; j += 4) {
        int s0 = __shfl(cidx, j + 0, 32);
        int s1 = __shfl(cidx, j + 1, 32);
        int s2 = __shfl(cidx, j + 2, 32);
        int s3 = __shfl(cidx, j + 3, 32);
        unsigned u0 = Gu[(size_t)s0 * 32 + hl];
        unsigned u1 = Gu[(size_t)s1 * 32 + hl];
        unsigned u2 = Gu[(size_t)s2 * 32 + hl];
        unsigned u3 = Gu[(size_t)s3 * 32 + hl];
        a0 += bflo(u0); a1 += bfhi(u0);
        b0 += bflo(u1); b1 += bfhi(u1);
        c0 += bflo(u2); c1 += bfhi(u2);
        d0 += bflo(u3); d1 += bfhi(u3);
    }
    for (; j < nfast; ++j) {
        int s0 = __shfl(cidx, j, 32);
        unsigned u0 = Gu[(size_t)s0 * 32 + hl];
        a0 += bflo(u0); a1 += bfhi(u0);
    }
    for (int e = beg + 32; e < end; ++e) {
        unsigned u0 = Gu[(size_t)col_idx[e] * 32 + hl];
        a0 += bflo(u0); a1 += bfhi(u0);
    }
    if (act) {
        unsigned us = Gu[(size_t)v * 32 + hl];
        float inv = deg_inv[v];
        float r0 = (a0 + b0 + c0 + d0 + bflo(us)) * inv + bias[hl * 2 + 0];
        float r1 = (a1 + b1 + c1 + d1 + bfhi(us)) * inv + bias[hl * 2 + 1];
        r0 = 1.0f / (1.0f + __expf(-r0));
        r1 = 1.0f / (1.0f + __expf(-r1));
        *(float2*)(out + (size_t)v * 64 + hl * 2) = make_float2(r0, r1);
    }
}

// ---------------------------------------------------------------------------

static inline size_t align256(size_t x) { return (x + 255) & ~(size_t)255; }

extern "C" void kernel_launch(void* const* d_in, const int* in_sizes, int n_in,
                              void* d_out, int out_size, void* d_ws, size_t ws_size,
                              hipStream_t stream) {
    const float* x   = (const float*)d_in[0];
    const int*   src = (const int*)d_in[1];
    const int*   dst = (const int*)d_in[2];
    const float* W1  = (const float*)d_in[3];
    const float* b1  = (const float*)d_in[4];
    const float* W2  = (const float*)d_in[5];
    const float* b2  = (const float*)d_in[6];
    const float* W3  = (const float*)d_in[7];
    const float* b3  = (const float*)d_in[8];
    float*       out = (float*)d_out;

    const int N = in_sizes[0] / NFEAT;     // 50000
    const int E = in_sizes[1];             // 800000
    const int D_OUT = in_sizes[7] / NFEAT; // 64
    const int NBUK = (N + (1 << BSH) - 1) >> BSH;   // 391
    const int PBLK = (E + EPB - 1) / EPB;           // 391

    // workspace carve:
    //   xbf: bf16 x (layer-1 gather src); gbf aliases xbf (x dead when written)
    //   h1bf: layer-1 out / layer-2 gather src; pairs (CSR, 6.4 MB) aliases it
    char* ws = (char*)d_ws;
    int* row_ptr      = (int*)ws;  ws += align256((size_t)(N + 1) * 4);
    int* col_idx      = (int*)ws;  ws += align256((size_t)E * 4);
    float* deg_inv    = (float*)ws; ws += align256((size_t)N * 4);
    int* bucketCnt    = (int*)ws;  ws += align256((size_t)NBUKP * 4);
    int* bucketOff    = (int*)ws;  ws += align256((size_t)NBUKP * 4);
    int* bucketCursor = (int*)ws;  ws += align256((size_t)NBUKP * 4);
    ushort* w1bf      = (ushort*)ws; ws += align256((size_t)NFEAT * NFEAT * 2);
    ushort* w2bf      = (ushort*)ws; ws += align256((size_t)NFEAT * NFEAT * 2);
    ushort* w3bf      = (ushort*)ws; ws += align256((size_t)D_OUT * NFEAT * 2);
    ushort* xbf       = (ushort*)ws; ws += align256((size_t)N * NFEAT * 2);
    ushort* h1bf      = (ushort*)ws; ws += align256((size_t)N * NFEAT * 2);
    ushort* gbf = xbf;                                      // x dead after fused<0>
    unsigned long long* pairs = (unsigned long long*)h1bf;  // dead before fused<0>

    // ---- CSR build via 2-level partition ----
    hipMemsetAsync(bucketCnt, 0, (size_t)NBUKP * 4, stream);
    partA1_count<<<PBLK, 256, 0, stream>>>(dst, bucketCnt, E);
    partA2_scan<<<1, NBUKP, 0, stream>>>(bucketCnt, bucketOff, bucketCursor, row_ptr, N, E);
    partA3_scatter<<<PBLK, 256, 0, stream>>>(src, dst, bucketCursor, pairs, E);
    partB_build<<<NBUK, 256, 0, stream>>>(pairs, bucketOff, bucketCnt, row_ptr, deg_inv, col_idx, N);

    // ---- convert x and weights to bf16 ----
    const int n4 = N * NFEAT / 4;
    cvt_bf16_kernel<<<(n4 + 255) / 256, 256, 0, stream>>>(x, xbf, n4);
    const int n1 = NFEAT * NFEAT / 4, n2 = NFEAT * NFEAT / 4, n3 = D_OUT * NFEAT / 4;
    cvt_weights_kernel<<<(n1 + n2 + n3 + 255) / 256, 256, 0, stream>>>(
        W1, W2, W3, w1bf, w2bf, w3bf, n1, n2, n3);

    const int fusedBlocks = (N + 15) / 16;   // 3125
    const int agg64Blocks = (N + 7) / 8;     // 2 nodes/wave

    // layer 1: agg(x) -> MFMA W1 + b1 + relu -> h1bf
    fused_agg_gemm_kernel<0><<<fusedBlocks, 256, 0, stream>>>(
        xbf, row_ptr, col_idx, deg_inv, w1bf, b1, nullptr, h1bf, N);
    // layers 2+3a: agg(h1) -> MFMA W2 + b2 + relu -> MFMA W3 -> gbf
    fused_agg_gemm_kernel<1><<<fusedBlocks, 256, 0, stream>>>(
        h1bf, row_ptr, col_idx, deg_inv, w2bf, b2, w3bf, gbf, N);
    // layer 3b: aggregate g + b3 + sigmoid -> out
    agg64_sigmoid_kernel<<<agg64Blocks, 256, 0, stream>>>(gbf, row_ptr, col_idx, deg_inv, b3, out, N);
}